// Round 1
// baseline (335.888 us; speedup 1.0000x reference)
//
#include <hip/hip_runtime.h>
#include <math.h>

// Problem dims
#define BSZ   256
#define LDIM  128
#define PDIM  3
#define HDIM  512
#define DDIM  32
#define NDIM  50
#define NEDGE 1225   // N*(N-1)/2
#define EOUT  5      // EDIM+1

// out layout (floats)
//   node_logits  [256,50,32]   @ 0        (409600)
//   edge_logits  [256,1225,5]  @ 409600   (1568000)
//   size_probs   [256,50]      @ 1977600  (12800)
//   edge_indices [1225,2]      @ 1990400  (2450, written as float values)

// ws layout (floats)
//   h    [256,512]      @ 0
//   n1   [256,512]      @ 131072
//   pW1  [50,512]       @ 262144
//   u    [256,512]      @ 287744
//   A    [256,50,512]   @ 418816
//   B    [256,50,512]   @ 6972416
//   iijj [1225,2] int   @ 13526016 (float offset)

// ---------------- input projection: h = relu([z|tp] @ W_in + b_in) ----------
__global__ void k_input(const float* __restrict__ z, const float* __restrict__ tp,
                        const float* __restrict__ W_in, const float* __restrict__ b_in,
                        float* __restrict__ h) {
    int b = blockIdx.x, t = threadIdx.x;   // block 512
    __shared__ float sin_[LDIM + PDIM];
    if (t < LDIM) sin_[t] = z[b * LDIM + t];
    else if (t < LDIM + PDIM) sin_[t] = tp[b * PDIM + (t - LDIM)];
    __syncthreads();
    float acc = b_in[t];
    for (int k = 0; k < LDIM + PDIM; ++k)
        acc += sin_[k] * W_in[k * HDIM + t];
    h[b * HDIM + t] = fmaxf(acc, 0.f);
}

// ---------------- size predictor head (fused, incl. softmax) ----------------
__global__ void k_size(const float* __restrict__ h,
                       const float* __restrict__ W_s1, const float* __restrict__ b_s1,
                       const float* __restrict__ W_s2, const float* __restrict__ b_s2,
                       float* __restrict__ out_sp) {
    int b = blockIdx.x, t = threadIdx.x;   // block 256
    __shared__ float sh[HDIM];
    __shared__ float ss[HDIM / 2];
    __shared__ float sl[NDIM];
    sh[t] = h[b * HDIM + t];
    sh[t + 256] = h[b * HDIM + t + 256];
    __syncthreads();
    float acc = b_s1[t];
    for (int k = 0; k < HDIM; ++k)
        acc += sh[k] * W_s1[k * (HDIM / 2) + t];
    ss[t] = fmaxf(acc, 0.f);
    __syncthreads();
    if (t < NDIM) {
        float a2 = b_s2[t];
        for (int k = 0; k < HDIM / 2; ++k)
            a2 += ss[k] * W_s2[k * NDIM + t];
        sl[t] = a2;
    }
    __syncthreads();
    if (t < NDIM) {
        float m = sl[0];
        for (int k = 1; k < NDIM; ++k) m = fmaxf(m, sl[k]);
        float s = 0.f;
        for (int k = 0; k < NDIM; ++k) s += expf(sl[k] - m);
        out_sp[b * NDIM + t] = expf(sl[t] - m) / s;
    }
}

// -------- generic [*,512] x [512,512] per-row GEMM: out = scale*(in@W) [+b][relu]
__global__ void k_gemm512(const float* __restrict__ in, const float* __restrict__ W,
                          const float* __restrict__ bias, float* __restrict__ out,
                          int relu, float scale) {
    int b = blockIdx.x, t = threadIdx.x;   // block 512
    __shared__ float sh[HDIM];
    sh[t] = in[b * HDIM + t];
    __syncthreads();
    float acc = 0.f;
    for (int k = 0; k < HDIM; ++k)
        acc += sh[k] * W[k * HDIM + t];
    acc *= scale;
    if (bias) acc += bias[t];
    if (relu) acc = fmaxf(acc, 0.f);
    out[b * HDIM + t] = acc;
}

// ---------------- node logits: nl = n1 @ W_n2 + b_n2  ([512]->[1600]) -------
__global__ void k_node(const float* __restrict__ n1, const float* __restrict__ W_n2,
                       const float* __restrict__ b_n2, float* __restrict__ out_nl) {
    int b = blockIdx.x, t = threadIdx.x;   // block 512
    __shared__ float sh[HDIM];
    sh[t] = n1[b * HDIM + t];
    __syncthreads();
    for (int j = t; j < NDIM * DDIM; j += 512) {
        float acc = b_n2[j];
        for (int k = 0; k < HDIM; ++k)
            acc += sh[k] * W_n2[k * (NDIM * DDIM) + j];
        out_nl[b * (NDIM * DDIM) + j] = acc;
    }
}

// ---------------- A/B precompute ------------------------------------------
// A[b,n,t] = nl[b,n]@W_e1[512:544,t] + pW1[n,t] + 0.5*(u[b,t]+b_e1[t])
// B[b,n,t] = nl[b,n]@W_e1[544:576,t] + pW1[n,t] + 0.5*(u[b,t]+b_e1[t])
__global__ void k_ab(const float* __restrict__ nl, const float* __restrict__ W_e1,
                     const float* __restrict__ u, const float* __restrict__ pW1,
                     const float* __restrict__ b_e1,
                     float* __restrict__ Aout, float* __restrict__ Bout) {
    int n = blockIdx.x;        // 50
    int bg = blockIdx.y;       // 16 groups of 16 batches
    int t = threadIdx.x;       // 512
    float wa[DDIM], wb[DDIM];
#pragma unroll
    for (int k = 0; k < DDIM; ++k) {
        wa[k] = W_e1[(HDIM + k) * HDIM + t];
        wb[k] = W_e1[(HDIM + DDIM + k) * HDIM + t];
    }
    float pwn = pW1[n * HDIM + t];
    float be = 0.5f * b_e1[t];
    __shared__ float snl[DDIM];
    for (int bi = 0; bi < 16; ++bi) {
        int b = bg * 16 + bi;
        __syncthreads();
        if (t < DDIM) snl[t] = nl[(b * NDIM + n) * DDIM + t];
        __syncthreads();
        float accA = 0.f, accB = 0.f;
#pragma unroll
        for (int k = 0; k < DDIM; ++k) {
            float x = snl[k];
            accA += x * wa[k];
            accB += x * wb[k];
        }
        float common = 0.5f * u[b * HDIM + t] + be + pwn;
        size_t o = ((size_t)b * NDIM + n) * HDIM + t;
        Aout[o] = accA + common;
        Bout[o] = accB + common;
    }
}

// ---------------- triu index table + edge_indices output -------------------
__global__ void k_iijj(int* __restrict__ iijj, float* __restrict__ out_idx) {
    int e = blockIdx.x * blockDim.x + threadIdx.x;
    if (e >= NEDGE) return;
    int i = 0, rem = e;
    while (rem >= (NDIM - 1 - i)) { rem -= (NDIM - 1 - i); ++i; }
    int j = i + 1 + rem;
    iijj[e * 2] = i;
    iijj[e * 2 + 1] = j;
    out_idx[e * 2] = (float)i;
    out_idx[e * 2 + 1] = (float)j;
}

// ---------------- edge MLP: one wave per edge ------------------------------
// v = relu(A[b,i,:] + B[b,j,:]);  out5 = v @ W_e2 + b_e2
__global__ __launch_bounds__(256) void k_edge(const float* __restrict__ A,
                                              const float* __restrict__ B,
                                              const int* __restrict__ iijj,
                                              const float* __restrict__ W_e2,
                                              const float* __restrict__ b_e2,
                                              float* __restrict__ out_e) {
    int b = blockIdx.y;
    int lane = threadIdx.x & 63;
    int wv = threadIdx.x >> 6;   // 4 waves/block

    // per-lane W_e2 slice: rows lane*8 .. lane*8+7 -> flat [lane*40, lane*40+40)
    float w[40];
    const float4* wp = reinterpret_cast<const float4*>(W_e2 + lane * 40);
#pragma unroll
    for (int q = 0; q < 10; ++q) {
        float4 v4 = wp[q];
        w[q * 4 + 0] = v4.x; w[q * 4 + 1] = v4.y;
        w[q * 4 + 2] = v4.z; w[q * 4 + 3] = v4.w;
    }
    float be0 = b_e2[0], be1 = b_e2[1], be2 = b_e2[2], be3 = b_e2[3], be4 = b_e2[4];

    const float* Ab = A + (size_t)b * NDIM * HDIM;
    const float* Bb = B + (size_t)b * NDIM * HDIM;

    for (int e = blockIdx.x * 4 + wv; e < NEDGE; e += gridDim.x * 4) {
        int i = iijj[e * 2], j = iijj[e * 2 + 1];
        const float* ar = Ab + i * HDIM + lane * 8;
        const float* br = Bb + j * HDIM + lane * 8;
        float4 a0 = *reinterpret_cast<const float4*>(ar);
        float4 a1 = *reinterpret_cast<const float4*>(ar + 4);
        float4 c0 = *reinterpret_cast<const float4*>(br);
        float4 c1 = *reinterpret_cast<const float4*>(br + 4);
        float v[8];
        v[0] = fmaxf(a0.x + c0.x, 0.f); v[1] = fmaxf(a0.y + c0.y, 0.f);
        v[2] = fmaxf(a0.z + c0.z, 0.f); v[3] = fmaxf(a0.w + c0.w, 0.f);
        v[4] = fmaxf(a1.x + c1.x, 0.f); v[5] = fmaxf(a1.y + c1.y, 0.f);
        v[6] = fmaxf(a1.z + c1.z, 0.f); v[7] = fmaxf(a1.w + c1.w, 0.f);
        float acc0 = 0.f, acc1 = 0.f, acc2 = 0.f, acc3 = 0.f, acc4 = 0.f;
#pragma unroll
        for (int r = 0; r < 8; ++r) {
            acc0 += v[r] * w[r * 5 + 0];
            acc1 += v[r] * w[r * 5 + 1];
            acc2 += v[r] * w[r * 5 + 2];
            acc3 += v[r] * w[r * 5 + 3];
            acc4 += v[r] * w[r * 5 + 4];
        }
#pragma unroll
        for (int off = 32; off > 0; off >>= 1) {
            acc0 += __shfl_down(acc0, off);
            acc1 += __shfl_down(acc1, off);
            acc2 += __shfl_down(acc2, off);
            acc3 += __shfl_down(acc3, off);
            acc4 += __shfl_down(acc4, off);
        }
        if (lane == 0) {
            size_t o = ((size_t)b * NEDGE + e) * EOUT;
            out_e[o + 0] = acc0 + be0;
            out_e[o + 1] = acc1 + be1;
            out_e[o + 2] = acc2 + be2;
            out_e[o + 3] = acc3 + be3;
            out_e[o + 4] = acc4 + be4;
        }
    }
}

extern "C" void kernel_launch(void* const* d_in, const int* in_sizes, int n_in,
                              void* d_out, int out_size, void* d_ws, size_t ws_size,
                              hipStream_t stream) {
    const float* z    = (const float*)d_in[0];
    const float* tp   = (const float*)d_in[1];
    const float* W_in = (const float*)d_in[2];
    const float* b_in = (const float*)d_in[3];
    const float* W_s1 = (const float*)d_in[4];
    const float* b_s1 = (const float*)d_in[5];
    const float* W_s2 = (const float*)d_in[6];
    const float* b_s2 = (const float*)d_in[7];
    const float* W_n1 = (const float*)d_in[8];
    const float* b_n1 = (const float*)d_in[9];
    const float* W_n2 = (const float*)d_in[10];
    const float* b_n2 = (const float*)d_in[11];
    const float* W_e1 = (const float*)d_in[12];
    const float* b_e1 = (const float*)d_in[13];
    const float* W_e2 = (const float*)d_in[14];
    const float* b_e2 = (const float*)d_in[15];
    const float* pe   = (const float*)d_in[16];

    float* out     = (float*)d_out;
    float* out_nl  = out;                 // node_logits
    float* out_el  = out + 409600;        // edge_logits
    float* out_sp  = out + 1977600;       // size_probs
    float* out_idx = out + 1990400;       // edge_indices (as float)

    float* ws   = (float*)d_ws;
    float* h    = ws;
    float* n1   = ws + 131072;
    float* pW1  = ws + 262144;
    float* u    = ws + 287744;
    float* Abuf = ws + 418816;
    float* Bbuf = ws + 6972416;
    int*   iijj = (int*)(ws + 13526016);

    k_input<<<BSZ, HDIM, 0, stream>>>(z, tp, W_in, b_in, h);
    k_size<<<BSZ, 256, 0, stream>>>(h, W_s1, b_s1, W_s2, b_s2, out_sp);
    k_gemm512<<<BSZ, HDIM, 0, stream>>>(h, W_n1, b_n1, n1, 1, 1.0f);
    k_node<<<BSZ, HDIM, 0, stream>>>(n1, W_n2, b_n2, out_nl);
    k_gemm512<<<BSZ, HDIM, 0, stream>>>(h, W_e1, nullptr, u, 0, 1.0f);   // u = h @ W1h
    k_gemm512<<<NDIM, HDIM, 0, stream>>>(pe, W_e1, nullptr, pW1, 0, 0.5f); // pW1 = 0.5*pe@W1h
    k_iijj<<<5, 256, 0, stream>>>(iijj, out_idx);
    k_ab<<<dim3(NDIM, 16), HDIM, 0, stream>>>(out_nl, W_e1, u, pW1, b_e1, Abuf, Bbuf);
    k_edge<<<dim3(64, BSZ), 256, 0, stream>>>(Abuf, Bbuf, iijj, W_e2, b_e2, out_el);
}

// Round 2
// 302.009 us; speedup vs baseline: 1.1122x; 1.1122x over previous
//
#include <hip/hip_runtime.h>
#include <math.h>

// Problem dims
#define BSZ   256
#define LDIM  128
#define PDIM  3
#define HDIM  512
#define DDIM  32
#define NDIM  50
#define NEDGE 1225   // N*(N-1)/2
#define EOUT  5      // EDIM+1

// out layout (floats)
//   node_logits  [256,50,32]   @ 0        (409600)
//   edge_logits  [256,1225,5]  @ 409600   (1568000)
//   size_probs   [256,50]      @ 1977600  (12800)
//   edge_indices [1225,2]      @ 1990400  (2450, written as float values)

// ws layout (floats)
//   h    [256,512]      @ 0
//   n1   [256,512]      @ 131072
//   pW1  [50,512]       @ 262144
//   u    [256,512]      @ 287744
//   A    [256,50,512]   @ 418816
//   B    [256,50,512]   @ 6972416

// ---------------- input projection: h = relu([z|tp] @ W_in + b_in) ----------
__global__ void k_input(const float* __restrict__ z, const float* __restrict__ tp,
                        const float* __restrict__ W_in, const float* __restrict__ b_in,
                        float* __restrict__ h) {
    int b = blockIdx.x, t = threadIdx.x;   // block 512
    __shared__ float sin_[LDIM + PDIM];
    if (t < LDIM) sin_[t] = z[b * LDIM + t];
    else if (t < LDIM + PDIM) sin_[t] = tp[b * PDIM + (t - LDIM)];
    __syncthreads();
    float acc = b_in[t];
    for (int k = 0; k < LDIM + PDIM; ++k)
        acc += sin_[k] * W_in[k * HDIM + t];
    h[b * HDIM + t] = fmaxf(acc, 0.f);
}

// ---------------- size predictor head (fused, incl. softmax) ----------------
__global__ void k_size(const float* __restrict__ h,
                       const float* __restrict__ W_s1, const float* __restrict__ b_s1,
                       const float* __restrict__ W_s2, const float* __restrict__ b_s2,
                       float* __restrict__ out_sp) {
    int b = blockIdx.x, t = threadIdx.x;   // block 256
    __shared__ float sh[HDIM];
    __shared__ float ss[HDIM / 2];
    __shared__ float sl[NDIM];
    sh[t] = h[b * HDIM + t];
    sh[t + 256] = h[b * HDIM + t + 256];
    __syncthreads();
    float acc = b_s1[t];
    for (int k = 0; k < HDIM; ++k)
        acc += sh[k] * W_s1[k * (HDIM / 2) + t];
    ss[t] = fmaxf(acc, 0.f);
    __syncthreads();
    if (t < NDIM) {
        float a2 = b_s2[t];
        for (int k = 0; k < HDIM / 2; ++k)
            a2 += ss[k] * W_s2[k * NDIM + t];
        sl[t] = a2;
    }
    __syncthreads();
    if (t < NDIM) {
        float m = sl[0];
        for (int k = 1; k < NDIM; ++k) m = fmaxf(m, sl[k]);
        float s = 0.f;
        for (int k = 0; k < NDIM; ++k) s += expf(sl[k] - m);
        out_sp[b * NDIM + t] = expf(sl[t] - m) / s;
    }
}

// -------- [R,512] x [512,512]: 2 batch rows per block, W read once/block ----
__global__ __launch_bounds__(512) void k_gemm512(const float* __restrict__ in,
                                                 const float* __restrict__ W,
                                                 const float* __restrict__ bias,
                                                 float* __restrict__ out,
                                                 int relu, float scale) {
    int bg = blockIdx.x, t = threadIdx.x;   // block 512, rows bg*2, bg*2+1
    __shared__ float ins[2 * HDIM];
    ins[t] = in[(size_t)(bg * 2) * HDIM + t];
    ins[HDIM + t] = in[(size_t)(bg * 2 + 1) * HDIM + t];
    __syncthreads();
    float acc0 = 0.f, acc1 = 0.f;
    for (int k4 = 0; k4 < HDIM / 4; ++k4) {
        float w0 = W[(size_t)(k4 * 4 + 0) * HDIM + t];
        float w1 = W[(size_t)(k4 * 4 + 1) * HDIM + t];
        float w2 = W[(size_t)(k4 * 4 + 2) * HDIM + t];
        float w3 = W[(size_t)(k4 * 4 + 3) * HDIM + t];
        float4 n0 = *reinterpret_cast<const float4*>(&ins[k4 * 4]);
        float4 n1v = *reinterpret_cast<const float4*>(&ins[HDIM + k4 * 4]);
        acc0 += n0.x * w0 + n0.y * w1 + n0.z * w2 + n0.w * w3;
        acc1 += n1v.x * w0 + n1v.y * w1 + n1v.z * w2 + n1v.w * w3;
    }
    acc0 *= scale; acc1 *= scale;
    if (bias) { acc0 += bias[t]; acc1 += bias[t]; }
    if (relu) { acc0 = fmaxf(acc0, 0.f); acc1 = fmaxf(acc1, 0.f); }
    out[(size_t)(bg * 2) * HDIM + t] = acc0;
    out[(size_t)(bg * 2 + 1) * HDIM + t] = acc1;
}

// ---------------- node logits: [256,512] @ [512,1600] + b ------------------
// block: 320 outputs x 8 batches; grid (5, 32)
__global__ __launch_bounds__(320) void k_node(const float* __restrict__ n1,
                                              const float* __restrict__ W_n2,
                                              const float* __restrict__ b_n2,
                                              float* __restrict__ out_nl) {
    const int NOUT = NDIM * DDIM;   // 1600
    int t = threadIdx.x;
    int j = blockIdx.x * 320 + t;
    int bg = blockIdx.y;            // 8 batches per group
    __shared__ float n1s[8 * HDIM];
    for (int idx = t; idx < 8 * HDIM / 4; idx += 320) {
        int lin = idx * 4;
        int row = lin >> 9, col = lin & 511;
        *reinterpret_cast<float4*>(&n1s[row * HDIM + col]) =
            *reinterpret_cast<const float4*>(&n1[(size_t)(bg * 8 + row) * HDIM + col]);
    }
    __syncthreads();
    float bias = b_n2[j];
    float acc[8];
#pragma unroll
    for (int b = 0; b < 8; ++b) acc[b] = bias;
    for (int k4 = 0; k4 < HDIM / 4; ++k4) {
        float w0 = W_n2[(size_t)(k4 * 4 + 0) * NOUT + j];
        float w1 = W_n2[(size_t)(k4 * 4 + 1) * NOUT + j];
        float w2 = W_n2[(size_t)(k4 * 4 + 2) * NOUT + j];
        float w3 = W_n2[(size_t)(k4 * 4 + 3) * NOUT + j];
#pragma unroll
        for (int b = 0; b < 8; ++b) {
            float4 nv = *reinterpret_cast<const float4*>(&n1s[b * HDIM + k4 * 4]);
            acc[b] += nv.x * w0 + nv.y * w1 + nv.z * w2 + nv.w * w3;
        }
    }
#pragma unroll
    for (int b = 0; b < 8; ++b)
        out_nl[(size_t)(bg * 8 + b) * NOUT + j] = acc[b];
}

// ---------------- A/B precompute ------------------------------------------
__global__ void k_ab(const float* __restrict__ nl, const float* __restrict__ W_e1,
                     const float* __restrict__ u, const float* __restrict__ pW1,
                     const float* __restrict__ b_e1,
                     float* __restrict__ Aout, float* __restrict__ Bout) {
    int n = blockIdx.x;        // 50
    int bg = blockIdx.y;       // 16 groups of 16 batches
    int t = threadIdx.x;       // 512
    float wa[DDIM], wb[DDIM];
#pragma unroll
    for (int k = 0; k < DDIM; ++k) {
        wa[k] = W_e1[(size_t)(HDIM + k) * HDIM + t];
        wb[k] = W_e1[(size_t)(HDIM + DDIM + k) * HDIM + t];
    }
    float pwn = pW1[n * HDIM + t];
    float be = 0.5f * b_e1[t];
    __shared__ float snl[DDIM];
    for (int bi = 0; bi < 16; ++bi) {
        int b = bg * 16 + bi;
        __syncthreads();
        if (t < DDIM) snl[t] = nl[((size_t)b * NDIM + n) * DDIM + t];
        __syncthreads();
        float accA = 0.f, accB = 0.f;
#pragma unroll
        for (int k = 0; k < DDIM; ++k) {
            float x = snl[k];
            accA += x * wa[k];
            accB += x * wb[k];
        }
        float common = 0.5f * u[(size_t)b * HDIM + t] + be + pwn;
        size_t o = ((size_t)b * NDIM + n) * HDIM + t;
        Aout[o] = accA + common;
        Bout[o] = accB + common;
    }
}

// ---------------- edge_indices output only ---------------------------------
__global__ void k_iijj(float* __restrict__ out_idx) {
    int e = blockIdx.x * blockDim.x + threadIdx.x;
    if (e >= NEDGE) return;
    int i = 0, rem = e;
    while (rem >= (NDIM - 1 - i)) { rem -= (NDIM - 1 - i); ++i; }
    int j = i + 1 + rem;
    out_idx[e * 2] = (float)i;
    out_idx[e * 2 + 1] = (float)j;
}

// ---------------- edge MLP: tiled, one thread per edge ---------------------
// block: one batch x one (i-tile, j-tile) pair of 16x16 nodes.
// A-tile and B-tile staged in LDS (pitch 516 -> conflict-free reads).
// Each thread owns edge (i,j): v = relu(A[i,:]+B[j,:]); out5 = v@W_e2 + b_e2.
// W_e2 read at wave-uniform addresses -> scalar path.
#define EPITCH 516
__device__ const int TPI[10] = {0, 0, 0, 0, 1, 1, 1, 2, 2, 3};
__device__ const int TPJ[10] = {0, 1, 2, 3, 1, 2, 3, 2, 3, 3};

__global__ __launch_bounds__(256) void k_edge(const float* __restrict__ A,
                                              const float* __restrict__ B,
                                              const float* __restrict__ W_e2,
                                              const float* __restrict__ b_e2,
                                              float* __restrict__ out_e) {
    int tp = blockIdx.x;       // 10 tile pairs
    int b  = blockIdx.y;       // 256 batches
    int t  = threadIdx.x;      // 256
    int ti = TPI[tp], tj = TPJ[tp];

    __shared__ float As[16 * EPITCH];
    __shared__ float Bs[16 * EPITCH];

    const float* Ab = A + (size_t)b * NDIM * HDIM;
    const float* Bb = B + (size_t)b * NDIM * HDIM;

    // stage 16 rows x 512 of A-tile and B-tile (rows clamped; invalid masked later)
    for (int q = 0; q < 8; ++q) {
        int lin = q * 1024 + t * 4;
        int row = lin >> 9, col = lin & 511;
        int ar = ti * 16 + row; if (ar > NDIM - 1) ar = NDIM - 1;
        int br = tj * 16 + row; if (br > NDIM - 1) br = NDIM - 1;
        *reinterpret_cast<float4*>(&As[row * EPITCH + col]) =
            *reinterpret_cast<const float4*>(&Ab[(size_t)ar * HDIM + col]);
        *reinterpret_cast<float4*>(&Bs[row * EPITCH + col]) =
            *reinterpret_cast<const float4*>(&Bb[(size_t)br * HDIM + col]);
    }
    __syncthreads();

    int il = t >> 4, jl = t & 15;
    int i = ti * 16 + il, j = tj * 16 + jl;
    bool valid = (i < j) && (j < NDIM);

    float acc0 = 0.f, acc1 = 0.f, acc2 = 0.f, acc3 = 0.f, acc4 = 0.f;
    const float* Arow = &As[il * EPITCH];
    const float* Brow = &Bs[jl * EPITCH];
    for (int r4 = 0; r4 < HDIM / 4; ++r4) {
        const float* wr = W_e2 + (size_t)(r4 * 4) * EOUT;   // uniform -> s_load
        float4 a4 = *reinterpret_cast<const float4*>(&Arow[r4 * 4]);
        float4 b4 = *reinterpret_cast<const float4*>(&Brow[r4 * 4]);
        float v0 = fmaxf(a4.x + b4.x, 0.f);
        float v1 = fmaxf(a4.y + b4.y, 0.f);
        float v2 = fmaxf(a4.z + b4.z, 0.f);
        float v3 = fmaxf(a4.w + b4.w, 0.f);
        acc0 += v0 * wr[0] + v1 * wr[5] + v2 * wr[10] + v3 * wr[15];
        acc1 += v0 * wr[1] + v1 * wr[6] + v2 * wr[11] + v3 * wr[16];
        acc2 += v0 * wr[2] + v1 * wr[7] + v2 * wr[12] + v3 * wr[17];
        acc3 += v0 * wr[3] + v1 * wr[8] + v2 * wr[13] + v3 * wr[18];
        acc4 += v0 * wr[4] + v1 * wr[9] + v2 * wr[14] + v3 * wr[19];
    }
    if (valid) {
        int e = i * (NDIM - 1) - (i * (i - 1)) / 2 + (j - i - 1);
        size_t o = ((size_t)b * NEDGE + e) * EOUT;
        out_e[o + 0] = acc0 + b_e2[0];
        out_e[o + 1] = acc1 + b_e2[1];
        out_e[o + 2] = acc2 + b_e2[2];
        out_e[o + 3] = acc3 + b_e2[3];
        out_e[o + 4] = acc4 + b_e2[4];
    }
}

extern "C" void kernel_launch(void* const* d_in, const int* in_sizes, int n_in,
                              void* d_out, int out_size, void* d_ws, size_t ws_size,
                              hipStream_t stream) {
    const float* z    = (const float*)d_in[0];
    const float* tp   = (const float*)d_in[1];
    const float* W_in = (const float*)d_in[2];
    const float* b_in = (const float*)d_in[3];
    const float* W_s1 = (const float*)d_in[4];
    const float* b_s1 = (const float*)d_in[5];
    const float* W_s2 = (const float*)d_in[6];
    const float* b_s2 = (const float*)d_in[7];
    const float* W_n1 = (const float*)d_in[8];
    const float* b_n1 = (const float*)d_in[9];
    const float* W_n2 = (const float*)d_in[10];
    const float* b_n2 = (const float*)d_in[11];
    const float* W_e1 = (const float*)d_in[12];
    const float* b_e1 = (const float*)d_in[13];
    const float* W_e2 = (const float*)d_in[14];
    const float* b_e2 = (const float*)d_in[15];
    const float* pe   = (const float*)d_in[16];

    float* out     = (float*)d_out;
    float* out_nl  = out;                 // node_logits
    float* out_el  = out + 409600;        // edge_logits
    float* out_sp  = out + 1977600;       // size_probs
    float* out_idx = out + 1990400;       // edge_indices (as float)

    float* ws   = (float*)d_ws;
    float* h    = ws;
    float* n1   = ws + 131072;
    float* pW1  = ws + 262144;
    float* u    = ws + 287744;
    float* Abuf = ws + 418816;
    float* Bbuf = ws + 6972416;

    k_input<<<BSZ, HDIM, 0, stream>>>(z, tp, W_in, b_in, h);
    k_size<<<BSZ, 256, 0, stream>>>(h, W_s1, b_s1, W_s2, b_s2, out_sp);
    k_gemm512<<<BSZ / 2, HDIM, 0, stream>>>(h, W_n1, b_n1, n1, 1, 1.0f);
    k_node<<<dim3(5, 32), 320, 0, stream>>>(n1, W_n2, b_n2, out_nl);
    k_gemm512<<<BSZ / 2, HDIM, 0, stream>>>(h, W_e1, nullptr, u, 0, 1.0f);   // u = h@W1h
    k_gemm512<<<NDIM / 2, HDIM, 0, stream>>>(pe, W_e1, nullptr, pW1, 0, 0.5f); // pW1
    k_iijj<<<5, 256, 0, stream>>>(out_idx);
    k_ab<<<dim3(NDIM, 16), HDIM, 0, stream>>>(out_nl, W_e1, u, pW1, b_e1, Abuf, Bbuf);
    k_edge<<<dim3(10, BSZ), 256, 0, stream>>>(Abuf, Bbuf, W_e2, b_e2, out_el);
}

// Round 3
// 237.703 us; speedup vs baseline: 1.4131x; 1.2705x over previous
//
#include <hip/hip_runtime.h>
#include <math.h>

// Problem dims
#define BSZ   256
#define LDIM  128
#define PDIM  3
#define HDIM  512
#define DDIM  32
#define NDIM  50
#define NEDGE 1225   // N*(N-1)/2
#define EOUT  5      // EDIM+1
#define CHUNK 128
#define NCH   4      // 512 / CHUNK

// out layout (floats)
//   node_logits  [256,50,32]   @ 0        (409600)
//   edge_logits  [256,1225,5]  @ 409600   (1568000)
//   size_probs   [256,50]      @ 1977600  (12800)
//   edge_indices [1225,2]      @ 1990400  (2450, written as float values)

// ws layout (floats): h @0, n1 @131072, u @262144, pW1 @393216

// ---------------- input projection: h = relu([z|tp] @ W_in + b_in) ----------
__global__ void k_input(const float* __restrict__ z, const float* __restrict__ tp,
                        const float* __restrict__ W_in, const float* __restrict__ b_in,
                        float* __restrict__ h) {
    int b = blockIdx.x, t = threadIdx.x;   // block 512
    __shared__ float sin_[LDIM + PDIM];
    if (t < LDIM) sin_[t] = z[b * LDIM + t];
    else if (t < LDIM + PDIM) sin_[t] = tp[b * PDIM + (t - LDIM)];
    __syncthreads();
    float acc = b_in[t];
    for (int k = 0; k < LDIM + PDIM; ++k)
        acc += sin_[k] * W_in[k * HDIM + t];
    h[b * HDIM + t] = fmaxf(acc, 0.f);
}

// ---------------- size predictor head (fused, incl. softmax) ----------------
__global__ void k_size(const float* __restrict__ h,
                       const float* __restrict__ W_s1, const float* __restrict__ b_s1,
                       const float* __restrict__ W_s2, const float* __restrict__ b_s2,
                       float* __restrict__ out_sp) {
    int b = blockIdx.x, t = threadIdx.x;   // block 256
    __shared__ float sh[HDIM];
    __shared__ float ss[HDIM / 2];
    __shared__ float sl[NDIM];
    sh[t] = h[b * HDIM + t];
    sh[t + 256] = h[b * HDIM + t + 256];
    __syncthreads();
    float acc = b_s1[t];
    for (int k = 0; k < HDIM; ++k)
        acc += sh[k] * W_s1[k * (HDIM / 2) + t];
    ss[t] = fmaxf(acc, 0.f);
    __syncthreads();
    if (t < NDIM) {
        float a2 = b_s2[t];
        for (int k = 0; k < HDIM / 2; ++k)
            a2 += ss[k] * W_s2[k * NDIM + t];
        sl[t] = a2;
    }
    __syncthreads();
    if (t < NDIM) {
        float m = sl[0];
        for (int k = 1; k < NDIM; ++k) m = fmaxf(m, sl[k]);
        float s = 0.f;
        for (int k = 0; k < NDIM; ++k) s += expf(sl[k] - m);
        out_sp[b * NDIM + t] = expf(sl[t] - m) / s;
    }
}

// ---- 3 GEMMs in one dispatch: y=0: n1=relu(h@W_n1+b); y=1: u=h@W1h; y=2: pW1=0.5*pe@W1h
__global__ __launch_bounds__(512) void k_gemm3(const float* __restrict__ h,
                                               const float* __restrict__ pe,
                                               const float* __restrict__ W_n1,
                                               const float* __restrict__ b_n1,
                                               const float* __restrict__ W_e1,
                                               float* __restrict__ n1,
                                               float* __restrict__ u,
                                               float* __restrict__ pW1) {
    int gy = blockIdx.y, bg = blockIdx.x, t = threadIdx.x;
    if (gy == 2 && bg >= 25) return;   // pe has 50 rows -> 25 blocks
    const float* in = (gy == 2) ? pe : h;
    const float* W  = (gy == 0) ? W_n1 : W_e1;  // W1h = first 512 rows of W_e1
    float* out      = (gy == 0) ? n1 : ((gy == 1) ? u : pW1);
    float scale     = (gy == 2) ? 0.5f : 1.0f;
    __shared__ float ins[2 * HDIM];
    int r0 = bg * 2, r1 = bg * 2 + 1;
    ins[t] = in[(size_t)r0 * HDIM + t];
    ins[HDIM + t] = in[(size_t)r1 * HDIM + t];
    __syncthreads();
    float a0 = 0.f, a1 = 0.f;
    for (int k4 = 0; k4 < HDIM / 4; ++k4) {
        float w0 = W[(size_t)(k4 * 4 + 0) * HDIM + t];
        float w1 = W[(size_t)(k4 * 4 + 1) * HDIM + t];
        float w2 = W[(size_t)(k4 * 4 + 2) * HDIM + t];
        float w3 = W[(size_t)(k4 * 4 + 3) * HDIM + t];
        float4 x0 = *reinterpret_cast<const float4*>(&ins[k4 * 4]);
        float4 x1 = *reinterpret_cast<const float4*>(&ins[HDIM + k4 * 4]);
        a0 += x0.x * w0 + x0.y * w1 + x0.z * w2 + x0.w * w3;
        a1 += x1.x * w0 + x1.y * w1 + x1.z * w2 + x1.w * w3;
    }
    a0 *= scale; a1 *= scale;
    if (gy == 0) {
        a0 = fmaxf(a0 + b_n1[t], 0.f);
        a1 = fmaxf(a1 + b_n1[t], 0.f);
    }
    out[(size_t)r0 * HDIM + t] = a0;
    out[(size_t)r1 * HDIM + t] = a1;
}

// ---------------- node logits: [256,512] @ [512,1600] + b ------------------
__global__ __launch_bounds__(320) void k_node(const float* __restrict__ n1,
                                              const float* __restrict__ W_n2,
                                              const float* __restrict__ b_n2,
                                              float* __restrict__ out_nl) {
    const int NOUT = NDIM * DDIM;   // 1600
    int t = threadIdx.x;
    int j = blockIdx.x * 320 + t;
    int bg = blockIdx.y;            // 8 batches per group
    __shared__ float n1s[8 * HDIM];
    for (int idx = t; idx < 8 * HDIM / 4; idx += 320) {
        int lin = idx * 4;
        int row = lin >> 9, col = lin & 511;
        *reinterpret_cast<float4*>(&n1s[row * HDIM + col]) =
            *reinterpret_cast<const float4*>(&n1[(size_t)(bg * 8 + row) * HDIM + col]);
    }
    __syncthreads();
    float bias = b_n2[j];
    float acc[8];
#pragma unroll
    for (int b = 0; b < 8; ++b) acc[b] = bias;
    for (int k4 = 0; k4 < HDIM / 4; ++k4) {
        float w0 = W_n2[(size_t)(k4 * 4 + 0) * NOUT + j];
        float w1 = W_n2[(size_t)(k4 * 4 + 1) * NOUT + j];
        float w2 = W_n2[(size_t)(k4 * 4 + 2) * NOUT + j];
        float w3 = W_n2[(size_t)(k4 * 4 + 3) * NOUT + j];
#pragma unroll
        for (int b = 0; b < 8; ++b) {
            float4 nv = *reinterpret_cast<const float4*>(&n1s[b * HDIM + k4 * 4]);
            acc[b] += nv.x * w0 + nv.y * w1 + nv.z * w2 + nv.w * w3;
        }
    }
#pragma unroll
    for (int b = 0; b < 8; ++b)
        out_nl[(size_t)(bg * 8 + b) * NOUT + j] = acc[b];
}

// ---------------- edge_indices output only ---------------------------------
__global__ void k_iijj(float* __restrict__ out_idx) {
    int e = blockIdx.x * blockDim.x + threadIdx.x;
    if (e >= NEDGE) return;
    int i = 0, rem = e;
    while (rem >= (NDIM - 1 - i)) { rem -= (NDIM - 1 - i); ++i; }
    int j = i + 1 + rem;
    out_idx[e * 2] = (float)i;
    out_idx[e * 2 + 1] = (float)j;
}

// ---------------- fused edge kernel ----------------------------------------
// One block per batch. Per CHUNK of 128 hidden cols:
//   phase A: recompute A[n,c], B[n,c] into LDS (XOR-swizzled granules)
//            A/B[n,c] = nl[b,n,:]@Wa/b[:,c] + pW1[n,c] + 0.5*(u[b,c]+b_e1[c])
//   phase B: 625 1x2-j-tile tasks accumulate out5 += relu(A_i+B_j)@W_e2 chunk
__global__ __launch_bounds__(640) void k_edgefused(
        const float* __restrict__ nl,    // [256,50,32]
        const float* __restrict__ u,     // [256,512]
        const float* __restrict__ pW1,   // [50,512]
        const float* __restrict__ W_e1,  // [576,512]
        const float* __restrict__ b_e1,  // [512]
        const float* __restrict__ W_e2,  // [512,5]
        const float* __restrict__ b_e2,  // [5]
        float* __restrict__ out_e) {
    int b = blockIdx.x;
    int t = threadIdx.x;

    __shared__ float As[NDIM * CHUNK];
    __shared__ float Bs[NDIM * CHUNK];

    // ---- task decode: 1x2 j-tiles, 625 tasks ----
    bool hasTask = (t < 625);
    int ti = 0, tj0 = 1;
    if (hasTask) {
        int rem = t, i = 0;
        while (rem >= ((NDIM - i) >> 1)) { rem -= (NDIM - i) >> 1; ++i; }
        ti = i; tj0 = i + 1 + 2 * rem;
    }
    bool e1ok = hasTask && (tj0 + 1 < NDIM);
    int tj1c = (tj0 + 1 < NDIM) ? (tj0 + 1) : (NDIM - 1);

    float acc0[EOUT] = {0.f, 0.f, 0.f, 0.f, 0.f};
    float acc1[EOUT] = {0.f, 0.f, 0.f, 0.f, 0.f};

    // phase-A role: threads 0..511 -> (nh, arr, c)
    bool pa = (t < 512);
    int nh  = t >> 8;           // n-half: [0,25) or [25,50)
    int arr = (t >> 7) & 1;     // 0 = A, 1 = B
    int c   = t & 127;
    const float4* nlb4 = reinterpret_cast<const float4*>(nl + (size_t)b * (NDIM * DDIM));

    for (int ch = 0; ch < NCH; ++ch) {
        int rc = ch * CHUNK;
        if (pa) {
            float w[DDIM];
#pragma unroll
            for (int k = 0; k < DDIM; ++k)
                w[k] = W_e1[(size_t)(HDIM + arr * DDIM + k) * HDIM + rc + c];
            float cm = 0.5f * (u[(size_t)b * HDIM + rc + c] + b_e1[rc + c]);
            float* dst = arr ? Bs : As;
            for (int n = nh * 25; n < nh * 25 + 25; ++n) {
                float acc = cm + pW1[(size_t)n * HDIM + rc + c];
#pragma unroll
                for (int q = 0; q < 8; ++q) {
                    float4 x = nlb4[n * 8 + q];   // uniform -> scalar loads
                    acc += x.x * w[4*q] + x.y * w[4*q+1] + x.z * w[4*q+2] + x.w * w[4*q+3];
                }
                dst[n * CHUNK + ((((c >> 2) ^ ((n >> 1) & 7)) << 2) | (c & 3))] = acc;
            }
        }
        __syncthreads();
        if (hasTask) {
            const float4* A4 = reinterpret_cast<const float4*>(As);
            const float4* B4 = reinterpret_cast<const float4*>(Bs);
            int bA = ti * (CHUNK / 4),   sA = (ti >> 1) & 7;
            int b0 = tj0 * (CHUNK / 4),  s0 = (tj0 >> 1) & 7;
            int b1 = tj1c * (CHUNK / 4), s1 = (tj1c >> 1) & 7;
            for (int r4 = 0; r4 < CHUNK / 4; ++r4) {
                const float* wr = W_e2 + (size_t)(rc + r4 * 4) * EOUT;  // uniform
                float4 av  = A4[bA + (r4 ^ sA)];
                float4 bv0 = B4[b0 + (r4 ^ s0)];
                float4 bv1 = B4[b1 + (r4 ^ s1)];
                float v0[4], v1[4];
                v0[0] = fmaxf(av.x + bv0.x, 0.f); v0[1] = fmaxf(av.y + bv0.y, 0.f);
                v0[2] = fmaxf(av.z + bv0.z, 0.f); v0[3] = fmaxf(av.w + bv0.w, 0.f);
                v1[0] = fmaxf(av.x + bv1.x, 0.f); v1[1] = fmaxf(av.y + bv1.y, 0.f);
                v1[2] = fmaxf(av.z + bv1.z, 0.f); v1[3] = fmaxf(av.w + bv1.w, 0.f);
#pragma unroll
                for (int rr = 0; rr < 4; ++rr) {
#pragma unroll
                    for (int o = 0; o < EOUT; ++o) {
                        float wv = wr[rr * EOUT + o];
                        acc0[o] += v0[rr] * wv;
                        acc1[o] += v1[rr] * wv;
                    }
                }
            }
        }
        __syncthreads();
    }

    if (hasTask) {
        int i = ti;
        int e0 = i * (NDIM - 1) - (i * (i - 1)) / 2 + (tj0 - i - 1);
        size_t o0 = ((size_t)b * NEDGE + e0) * EOUT;
#pragma unroll
        for (int o = 0; o < EOUT; ++o) out_e[o0 + o] = acc0[o] + b_e2[o];
        if (e1ok) {
            size_t o1 = o0 + EOUT;   // edge (i, tj0+1) is the next index
#pragma unroll
            for (int o = 0; o < EOUT; ++o) out_e[o1 + o] = acc1[o] + b_e2[o];
        }
    }
}

extern "C" void kernel_launch(void* const* d_in, const int* in_sizes, int n_in,
                              void* d_out, int out_size, void* d_ws, size_t ws_size,
                              hipStream_t stream) {
    const float* z    = (const float*)d_in[0];
    const float* tp   = (const float*)d_in[1];
    const float* W_in = (const float*)d_in[2];
    const float* b_in = (const float*)d_in[3];
    const float* W_s1 = (const float*)d_in[4];
    const float* b_s1 = (const float*)d_in[5];
    const float* W_s2 = (const float*)d_in[6];
    const float* b_s2 = (const float*)d_in[7];
    const float* W_n1 = (const float*)d_in[8];
    const float* b_n1 = (const float*)d_in[9];
    const float* W_n2 = (const float*)d_in[10];
    const float* b_n2 = (const float*)d_in[11];
    const float* W_e1 = (const float*)d_in[12];
    const float* b_e1 = (const float*)d_in[13];
    const float* W_e2 = (const float*)d_in[14];
    const float* b_e2 = (const float*)d_in[15];
    const float* pe   = (const float*)d_in[16];

    float* out     = (float*)d_out;
    float* out_nl  = out;                 // node_logits
    float* out_el  = out + 409600;        // edge_logits
    float* out_sp  = out + 1977600;       // size_probs
    float* out_idx = out + 1990400;       // edge_indices (as float)

    float* ws  = (float*)d_ws;
    float* h   = ws;
    float* n1  = ws + 131072;
    float* u   = ws + 262144;
    float* pW1 = ws + 393216;

    k_input<<<BSZ, HDIM, 0, stream>>>(z, tp, W_in, b_in, h);
    k_size<<<BSZ, 256, 0, stream>>>(h, W_s1, b_s1, W_s2, b_s2, out_sp);
    k_gemm3<<<dim3(128, 3), 512, 0, stream>>>(h, pe, W_n1, b_n1, W_e1, n1, u, pW1);
    k_node<<<dim3(5, 32), 320, 0, stream>>>(n1, W_n2, b_n2, out_nl);
    k_iijj<<<5, 256, 0, stream>>>(out_idx);
    k_edgefused<<<BSZ, 640, 0, stream>>>(out_nl, u, pW1, W_e1, b_e1, W_e2, b_e2, out_el);
}

// Round 4
// 201.373 us; speedup vs baseline: 1.6680x; 1.1804x over previous
//
#include <hip/hip_runtime.h>
#include <math.h>

// Problem dims
#define BSZ   256
#define LDIM  128
#define PDIM  3
#define HDIM  512
#define DDIM  32
#define NDIM  50
#define NEDGE 1225   // N*(N-1)/2
#define EOUT  5      // EDIM+1
#define CH    128    // edge chunk
#define NCH   4      // 512 / CH

// out layout (floats)
//   node_logits  [256,50,32]   @ 0        (409600)
//   edge_logits  [256,1225,5]  @ 409600   (1568000)
//   size_probs   [256,50]      @ 1977600  (12800)
//   edge_indices [1225,2]      @ 1990400  (2450, float values)
// ws layout (floats): h @0, n1 @131072, u @262144, pW1 @393216

// ============ k_head: input proj + size head + softmax + edge_indices ======
// grid 64 blocks x 512 threads; 4 batches per block.
__global__ __launch_bounds__(512) void k_head(
        const float* __restrict__ z, const float* __restrict__ tp,
        const float* __restrict__ W_in, const float* __restrict__ b_in,
        const float* __restrict__ W_s1, const float* __restrict__ b_s1,
        const float* __restrict__ W_s2, const float* __restrict__ b_s2,
        float* __restrict__ h, float* __restrict__ out_sp,
        float* __restrict__ out_idx) {
    int bg = blockIdx.x, t = threadIdx.x;
    __shared__ float s_in[4 * 131];
    __shared__ float s_h[4][HDIM];
    __shared__ float s_s1[4][HDIM / 2];
    __shared__ float s_lg[4][NDIM];

    for (int idx = t; idx < 4 * 131; idx += 512) {
        int bi = idx / 131, k = idx % 131;
        s_in[idx] = (k < LDIM) ? z[(size_t)(bg * 4 + bi) * LDIM + k]
                               : tp[(size_t)(bg * 4 + bi) * PDIM + (k - LDIM)];
    }
    __syncthreads();

    // phase 1: h = relu([z|tp]@W_in + b_in), 4 batches
    {
        float bin = b_in[t];
        float a0 = bin, a1 = bin, a2 = bin, a3 = bin;
        for (int k = 0; k < LDIM + PDIM; ++k) {
            float w = W_in[(size_t)k * HDIM + t];
            a0 += s_in[0 * 131 + k] * w;
            a1 += s_in[1 * 131 + k] * w;
            a2 += s_in[2 * 131 + k] * w;
            a3 += s_in[3 * 131 + k] * w;
        }
        a0 = fmaxf(a0, 0.f); a1 = fmaxf(a1, 0.f);
        a2 = fmaxf(a2, 0.f); a3 = fmaxf(a3, 0.f);
        s_h[0][t] = a0; s_h[1][t] = a1; s_h[2][t] = a2; s_h[3][t] = a3;
        h[(size_t)(bg * 4 + 0) * HDIM + t] = a0;
        h[(size_t)(bg * 4 + 1) * HDIM + t] = a1;
        h[(size_t)(bg * 4 + 2) * HDIM + t] = a2;
        h[(size_t)(bg * 4 + 3) * HDIM + t] = a3;
    }
    __syncthreads();

    // phase 2: s1 = relu(h@W_s1 + b_s1) -> [4][256]
    {
        int c = t & 255, bp = t >> 8;   // bp in {0,1} -> batches 2bp, 2bp+1
        float bv = b_s1[c];
        float a0 = bv, a1 = bv;
        for (int k = 0; k < HDIM; ++k) {
            float w = W_s1[(size_t)k * (HDIM / 2) + c];
            a0 += s_h[2 * bp][k] * w;
            a1 += s_h[2 * bp + 1][k] * w;
        }
        s_s1[2 * bp][c] = fmaxf(a0, 0.f);
        s_s1[2 * bp + 1][c] = fmaxf(a1, 0.f);
    }
    __syncthreads();

    // phase 3: logits = s1@W_s2 + b_s2 -> [4][50]
    int b4 = t / NDIM, o = t % NDIM;
    if (t < 4 * NDIM) {
        float a = b_s2[o];
        for (int k = 0; k < HDIM / 2; ++k)
            a += s_s1[b4][k] * W_s2[(size_t)k * NDIM + o];
        s_lg[b4][o] = a;
    }
    __syncthreads();

    // phase 4: softmax
    if (t < 4 * NDIM) {
        float m = s_lg[b4][0];
        for (int k = 1; k < NDIM; ++k) m = fmaxf(m, s_lg[b4][k]);
        float s = 0.f;
        for (int k = 0; k < NDIM; ++k) s += expf(s_lg[b4][k] - m);
        out_sp[(size_t)(bg * 4 + b4) * NDIM + o] = expf(s_lg[b4][o] - m) / s;
    }

    // edge_indices (block 0 only)
    if (bg == 0) {
        for (int e = t; e < NEDGE; e += 512) {
            int i = 0, rem = e;
            while (rem >= (NDIM - 1 - i)) { rem -= (NDIM - 1 - i); ++i; }
            int j = i + 1 + rem;
            out_idx[e * 2] = (float)i;
            out_idx[e * 2 + 1] = (float)j;
        }
    }
}

// ============ k_mid: n1 / u / pW1 GEMMs, batch-grouped x4 ==================
// blocks 0..63: n1 rows; 64..127: u rows; 128..140: pW1 (pe rows, x0.5)
__global__ __launch_bounds__(512) void k_mid(
        const float* __restrict__ h, const float* __restrict__ pe,
        const float* __restrict__ W_n1, const float* __restrict__ b_n1,
        const float* __restrict__ W_e1,
        float* __restrict__ n1, float* __restrict__ u, float* __restrict__ pW1) {
    int bx = blockIdx.x, t = threadIdx.x;
    int mode, r0;
    if (bx < 64)       { mode = 0; r0 = bx * 4; }
    else if (bx < 128) { mode = 1; r0 = (bx - 64) * 4; }
    else               { mode = 2; r0 = (bx - 128) * 4; }
    const float* in = (mode == 2) ? pe : h;
    const float* W  = (mode == 0) ? W_n1 : W_e1;   // W1h = first 512 rows of W_e1
    int nrows = (mode == 2) ? NDIM : BSZ;
    int r[4];
#pragma unroll
    for (int q = 0; q < 4; ++q) { int rr = r0 + q; r[q] = (rr < nrows) ? rr : nrows - 1; }

    __shared__ float s_x[4][HDIM];
    for (int idx = t; idx < 4 * HDIM; idx += 512)
        s_x[idx >> 9][idx & 511] = in[(size_t)r[idx >> 9] * HDIM + (idx & 511)];
    __syncthreads();

    float a0 = 0.f, a1 = 0.f, a2 = 0.f, a3 = 0.f;
    for (int k4 = 0; k4 < HDIM / 4; ++k4) {
        float w0 = W[(size_t)(k4 * 4 + 0) * HDIM + t];
        float w1 = W[(size_t)(k4 * 4 + 1) * HDIM + t];
        float w2 = W[(size_t)(k4 * 4 + 2) * HDIM + t];
        float w3 = W[(size_t)(k4 * 4 + 3) * HDIM + t];
        float4 x0 = *reinterpret_cast<const float4*>(&s_x[0][k4 * 4]);
        float4 x1 = *reinterpret_cast<const float4*>(&s_x[1][k4 * 4]);
        float4 x2 = *reinterpret_cast<const float4*>(&s_x[2][k4 * 4]);
        float4 x3 = *reinterpret_cast<const float4*>(&s_x[3][k4 * 4]);
        a0 += x0.x * w0 + x0.y * w1 + x0.z * w2 + x0.w * w3;
        a1 += x1.x * w0 + x1.y * w1 + x1.z * w2 + x1.w * w3;
        a2 += x2.x * w0 + x2.y * w1 + x2.z * w2 + x2.w * w3;
        a3 += x3.x * w0 + x3.y * w1 + x3.z * w2 + x3.w * w3;
    }
    float av[4] = {a0, a1, a2, a3};
    if (mode == 0) {
        float bb = b_n1[t];
#pragma unroll
        for (int q = 0; q < 4; ++q)
            n1[(size_t)r[q] * HDIM + t] = fmaxf(av[q] + bb, 0.f);
    } else if (mode == 1) {
#pragma unroll
        for (int q = 0; q < 4; ++q)
            u[(size_t)r[q] * HDIM + t] = av[q];
    } else {
#pragma unroll
        for (int q = 0; q < 4; ++q)
            pW1[(size_t)r[q] * HDIM + t] = 0.5f * av[q];
    }
}

// ============ k_node: [256,512]@[512,1600]+b, 4 batches/block ==============
__global__ __launch_bounds__(320) void k_node(const float* __restrict__ n1,
                                              const float* __restrict__ W_n2,
                                              const float* __restrict__ b_n2,
                                              float* __restrict__ out_nl) {
    const int NOUT = NDIM * DDIM;   // 1600
    int t = threadIdx.x;
    int j = blockIdx.x * 320 + t;
    int bg = blockIdx.y;            // 4 batches
    __shared__ float s[4 * HDIM];
    for (int idx = t; idx < 4 * HDIM / 4; idx += 320) {
        int lin = idx * 4;
        int row = lin >> 9, col = lin & 511;
        *reinterpret_cast<float4*>(&s[row * HDIM + col]) =
            *reinterpret_cast<const float4*>(&n1[(size_t)(bg * 4 + row) * HDIM + col]);
    }
    __syncthreads();
    float bias = b_n2[j];
    float acc[4] = {bias, bias, bias, bias};
    for (int k4 = 0; k4 < HDIM / 4; ++k4) {
        float w0 = W_n2[(size_t)(k4 * 4 + 0) * NOUT + j];
        float w1 = W_n2[(size_t)(k4 * 4 + 1) * NOUT + j];
        float w2 = W_n2[(size_t)(k4 * 4 + 2) * NOUT + j];
        float w3 = W_n2[(size_t)(k4 * 4 + 3) * NOUT + j];
#pragma unroll
        for (int b = 0; b < 4; ++b) {
            float4 nv = *reinterpret_cast<const float4*>(&s[b * HDIM + k4 * 4]);
            acc[b] += nv.x * w0 + nv.y * w1 + nv.z * w2 + nv.w * w3;
        }
    }
#pragma unroll
    for (int b = 0; b < 4; ++b)
        out_nl[(size_t)(bg * 4 + b) * NOUT + j] = acc[b];
}

// ============ fused edge kernel: producer/consumer pipeline ================
// 1024 threads. Waves 0-7 (t<512): producers — recompute A/B chunk ch+1 into
// LDS double buffer. Waves 8-15: consumers — 425 tasks of 1x3 j-tiles over
// chunk ch. One barrier per chunk.
__global__ __launch_bounds__(1024) void k_edgefused(
        const float* __restrict__ nl,    // [256,50,32]
        const float* __restrict__ u,     // [256,512]
        const float* __restrict__ pW1,   // [50,512]
        const float* __restrict__ W_e1,  // [576,512]
        const float* __restrict__ b_e1,  // [512]
        const float* __restrict__ W_e2,  // [512,5]
        const float* __restrict__ b_e2,  // [5]
        float* __restrict__ out_e) {
    int b = blockIdx.x;
    int t = threadIdx.x;

    __shared__ float As[2][NDIM * CH];   // 2 x 25.6 KB
    __shared__ float Bs[2][NDIM * CH];

    bool isProd = (t < 512);
    int nh  = (t >> 8) & 1;     // producer: n-half
    int arr = (t >> 7) & 1;     // producer: 0=A 1=B
    int c   = t & 127;          // producer: col within chunk

    int ct = t - 512;
    bool hasTask = (!isProd) && (ct < 425);
    int ti = 0, j0 = 1;
    if (hasTask) {
        int rem = ct, i = 0;
        while (rem >= (NDIM - 1 - i + 2) / 3) { rem -= (NDIM - 1 - i + 2) / 3; ++i; }
        ti = i; j0 = i + 1 + 3 * rem;
    }
    bool ok1 = hasTask && (j0 + 1 < NDIM);
    bool ok2 = hasTask && (j0 + 2 < NDIM);
    int j1 = (j0 + 1 < NDIM) ? j0 + 1 : NDIM - 1;
    int j2 = (j0 + 2 < NDIM) ? j0 + 2 : NDIM - 1;

    float acc0[EOUT] = {0.f, 0.f, 0.f, 0.f, 0.f};
    float acc1[EOUT] = {0.f, 0.f, 0.f, 0.f, 0.f};
    float acc2[EOUT] = {0.f, 0.f, 0.f, 0.f, 0.f};

    const float4* nlb4 = reinterpret_cast<const float4*>(nl + (size_t)b * (NDIM * DDIM));

    auto produce = [&](int ch, int buf) {
        float w[DDIM];
#pragma unroll
        for (int k = 0; k < DDIM; ++k)
            w[k] = W_e1[(size_t)(HDIM + arr * DDIM + k) * HDIM + ch * CH + c];
        float cm = 0.5f * (u[(size_t)b * HDIM + ch * CH + c] + b_e1[ch * CH + c]);
        float* dst = arr ? Bs[buf] : As[buf];
        for (int n = nh * 25; n < nh * 25 + 25; ++n) {
            float a = cm + pW1[(size_t)n * HDIM + ch * CH + c];
#pragma unroll
            for (int q = 0; q < 8; ++q) {
                float4 x = nlb4[n * 8 + q];   // wave-uniform -> s_load
                a += x.x * w[4*q] + x.y * w[4*q+1] + x.z * w[4*q+2] + x.w * w[4*q+3];
            }
            dst[n * CH + ((((c >> 2) ^ ((n >> 1) & 7)) << 2) | (c & 3))] = a;
        }
    };

    if (isProd) produce(0, 0);
    __syncthreads();

    for (int ch = 0; ch < NCH; ++ch) {
        int buf = ch & 1;
        if (hasTask) {
            const float4* A4 = reinterpret_cast<const float4*>(As[buf]);
            const float4* B4 = reinterpret_cast<const float4*>(Bs[buf]);
            int aB = ti * 32,  aS = (ti >> 1) & 7;
            int b0 = j0 * 32,  s0 = (j0 >> 1) & 7;
            int b1 = j1 * 32,  s1 = (j1 >> 1) & 7;
            int b2 = j2 * 32,  s2 = (j2 >> 1) & 7;
            const float* wch = W_e2 + (size_t)ch * CH * EOUT;
            for (int r4 = 0; r4 < CH / 4; ++r4) {
                const float* wr = wch + r4 * 4 * EOUT;   // uniform
                float4 av  = A4[aB + (r4 ^ aS)];
                float4 bv0 = B4[b0 + (r4 ^ s0)];
                float4 bv1 = B4[b1 + (r4 ^ s1)];
                float4 bv2 = B4[b2 + (r4 ^ s2)];
                float v0[4], v1[4], v2[4];
                v0[0] = fmaxf(av.x + bv0.x, 0.f); v0[1] = fmaxf(av.y + bv0.y, 0.f);
                v0[2] = fmaxf(av.z + bv0.z, 0.f); v0[3] = fmaxf(av.w + bv0.w, 0.f);
                v1[0] = fmaxf(av.x + bv1.x, 0.f); v1[1] = fmaxf(av.y + bv1.y, 0.f);
                v1[2] = fmaxf(av.z + bv1.z, 0.f); v1[3] = fmaxf(av.w + bv1.w, 0.f);
                v2[0] = fmaxf(av.x + bv2.x, 0.f); v2[1] = fmaxf(av.y + bv2.y, 0.f);
                v2[2] = fmaxf(av.z + bv2.z, 0.f); v2[3] = fmaxf(av.w + bv2.w, 0.f);
#pragma unroll
                for (int rr = 0; rr < 4; ++rr) {
#pragma unroll
                    for (int o = 0; o < EOUT; ++o) {
                        float wv = wr[rr * EOUT + o];
                        acc0[o] += v0[rr] * wv;
                        acc1[o] += v1[rr] * wv;
                        acc2[o] += v2[rr] * wv;
                    }
                }
            }
        }
        if (isProd && ch < NCH - 1) produce(ch + 1, buf ^ 1);
        __syncthreads();
    }

    if (hasTask) {
        int e0 = ti * (NDIM - 1) - (ti * (ti - 1)) / 2 + (j0 - ti - 1);
        size_t o = ((size_t)b * NEDGE + e0) * EOUT;
#pragma unroll
        for (int q = 0; q < EOUT; ++q) out_e[o + q] = acc0[q] + b_e2[q];
        if (ok1) {
#pragma unroll
            for (int q = 0; q < EOUT; ++q) out_e[o + EOUT + q] = acc1[q] + b_e2[q];
        }
        if (ok2) {
#pragma unroll
            for (int q = 0; q < EOUT; ++q) out_e[o + 2 * EOUT + q] = acc2[q] + b_e2[q];
        }
    }
}

extern "C" void kernel_launch(void* const* d_in, const int* in_sizes, int n_in,
                              void* d_out, int out_size, void* d_ws, size_t ws_size,
                              hipStream_t stream) {
    const float* z    = (const float*)d_in[0];
    const float* tp   = (const float*)d_in[1];
    const float* W_in = (const float*)d_in[2];
    const float* b_in = (const float*)d_in[3];
    const float* W_s1 = (const float*)d_in[4];
    const float* b_s1 = (const float*)d_in[5];
    const float* W_s2 = (const float*)d_in[6];
    const float* b_s2 = (const float*)d_in[7];
    const float* W_n1 = (const float*)d_in[8];
    const float* b_n1 = (const float*)d_in[9];
    const float* W_n2 = (const float*)d_in[10];
    const float* b_n2 = (const float*)d_in[11];
    const float* W_e1 = (const float*)d_in[12];
    const float* b_e1 = (const float*)d_in[13];
    const float* W_e2 = (const float*)d_in[14];
    const float* b_e2 = (const float*)d_in[15];
    const float* pe   = (const float*)d_in[16];

    float* out     = (float*)d_out;
    float* out_nl  = out;                 // node_logits
    float* out_el  = out + 409600;        // edge_logits
    float* out_sp  = out + 1977600;       // size_probs
    float* out_idx = out + 1990400;       // edge_indices (as float)

    float* ws  = (float*)d_ws;
    float* h   = ws;
    float* n1  = ws + 131072;
    float* u   = ws + 262144;
    float* pW1 = ws + 393216;

    k_head<<<64, 512, 0, stream>>>(z, tp, W_in, b_in, W_s1, b_s1, W_s2, b_s2,
                                   h, out_sp, out_idx);
    k_mid<<<141, 512, 0, stream>>>(h, pe, W_n1, b_n1, W_e1, n1, u, pW1);
    k_node<<<dim3(5, 64), 320, 0, stream>>>(n1, W_n2, b_n2, out_nl);
    k_edgefused<<<BSZ, 1024, 0, stream>>>(out_nl, u, pW1, W_e1, b_e1, W_e2, b_e2, out_el);
}

// Round 5
// 163.076 us; speedup vs baseline: 2.0597x; 1.2348x over previous
//
#include <hip/hip_runtime.h>
#include <math.h>

// Problem dims
#define BSZ   256
#define LDIM  128
#define PDIM  3
#define HDIM  512
#define DDIM  32
#define NDIM  50
#define NEDGE 1225   // N*(N-1)/2
#define EOUT  5      // EDIM+1
#define CH    128    // edge chunk cols

// out layout (floats)
//   node_logits  [256,50,32]   @ 0        (409600)
//   edge_logits  [256,1225,5]  @ 409600   (1568000)
//   size_probs   [256,50]      @ 1977600  (12800)
//   edge_indices [1225,2]      @ 1990400  (2450, float values)
// ws layout (floats): u @0 (131072), pW1 @131072 (25600), P @163840 (2x1568000)

// ============ k_front: entire pre-edge network in one dispatch =============
// block roles: [0,128) nl (2 batches), [128,192) u (4 batches),
//              [192,256) size head (4 batches), [256,269) pW1 (4 rows)
__global__ __launch_bounds__(512) void k_front(
        const float* __restrict__ z, const float* __restrict__ tp,
        const float* __restrict__ W_in, const float* __restrict__ b_in,
        const float* __restrict__ W_s1, const float* __restrict__ b_s1,
        const float* __restrict__ W_s2, const float* __restrict__ b_s2,
        const float* __restrict__ W_n1, const float* __restrict__ b_n1,
        const float* __restrict__ W_n2, const float* __restrict__ b_n2,
        const float* __restrict__ W_e1, const float* __restrict__ pe,
        float* __restrict__ out_nl, float* __restrict__ out_sp,
        float* __restrict__ u, float* __restrict__ pW1) {
    int bx = blockIdx.x, t = threadIdx.x;
    __shared__ float sA[4][HDIM];
    __shared__ float sB[4][HDIM];

    if (bx < 128) {
        // ---------------- role nl: h -> n1 -> node_logits, 2 batches -------
        int b0 = bx * 2;
        float* sin_ = &sB[2][0];   // 262 floats
        for (int idx = t; idx < 2 * 131; idx += 512) {
            int bi = idx / 131, k = idx % 131;
            sin_[idx] = (k < LDIM) ? z[(size_t)(b0 + bi) * LDIM + k]
                                   : tp[(size_t)(b0 + bi) * PDIM + (k - LDIM)];
        }
        __syncthreads();
        {
            float bin = b_in[t];
            float a0 = bin, a1 = bin;
            for (int k = 0; k < LDIM + PDIM; ++k) {
                float w = W_in[(size_t)k * HDIM + t];
                a0 += sin_[k] * w;
                a1 += sin_[131 + k] * w;
            }
            sA[0][t] = fmaxf(a0, 0.f);
            sA[1][t] = fmaxf(a1, 0.f);
        }
        __syncthreads();
        {
            float a0 = 0.f, a1 = 0.f;
            for (int k4 = 0; k4 < HDIM / 4; ++k4) {
                float w0 = W_n1[(size_t)(k4 * 4 + 0) * HDIM + t];
                float w1 = W_n1[(size_t)(k4 * 4 + 1) * HDIM + t];
                float w2 = W_n1[(size_t)(k4 * 4 + 2) * HDIM + t];
                float w3 = W_n1[(size_t)(k4 * 4 + 3) * HDIM + t];
                float4 x0 = *reinterpret_cast<const float4*>(&sA[0][k4 * 4]);
                float4 x1 = *reinterpret_cast<const float4*>(&sA[1][k4 * 4]);
                a0 += x0.x * w0 + x0.y * w1 + x0.z * w2 + x0.w * w3;
                a1 += x1.x * w0 + x1.y * w1 + x1.z * w2 + x1.w * w3;
            }
            float bb = b_n1[t];
            sB[0][t] = fmaxf(a0 + bb, 0.f);
            sB[1][t] = fmaxf(a1 + bb, 0.f);
        }
        __syncthreads();
        const int NOUT = NDIM * DDIM;   // 1600
        for (int pass = 0; pass < 4; ++pass) {
            int j = t + 512 * pass;
            if (j < NOUT) {
                float bb = b_n2[j];
                float a0 = bb, a1 = bb;
                for (int k4 = 0; k4 < HDIM / 4; ++k4) {
                    float w0 = W_n2[(size_t)(k4 * 4 + 0) * NOUT + j];
                    float w1 = W_n2[(size_t)(k4 * 4 + 1) * NOUT + j];
                    float w2 = W_n2[(size_t)(k4 * 4 + 2) * NOUT + j];
                    float w3 = W_n2[(size_t)(k4 * 4 + 3) * NOUT + j];
                    float4 x0 = *reinterpret_cast<const float4*>(&sB[0][k4 * 4]);
                    float4 x1 = *reinterpret_cast<const float4*>(&sB[1][k4 * 4]);
                    a0 += x0.x * w0 + x0.y * w1 + x0.z * w2 + x0.w * w3;
                    a1 += x1.x * w0 + x1.y * w1 + x1.z * w2 + x1.w * w3;
                }
                out_nl[(size_t)b0 * NOUT + j] = a0;
                out_nl[(size_t)(b0 + 1) * NOUT + j] = a1;
            }
        }
    } else if (bx < 192) {
        // ---------------- role u: h -> u = h@W1h, 4 batches ----------------
        int b0 = (bx - 128) * 4;
        float* sin_ = &sB[0][0];   // 524 floats
        for (int idx = t; idx < 4 * 131; idx += 512) {
            int bi = idx / 131, k = idx % 131;
            sin_[idx] = (k < LDIM) ? z[(size_t)(b0 + bi) * LDIM + k]
                                   : tp[(size_t)(b0 + bi) * PDIM + (k - LDIM)];
        }
        __syncthreads();
        {
            float bin = b_in[t];
            float a0 = bin, a1 = bin, a2 = bin, a3 = bin;
            for (int k = 0; k < LDIM + PDIM; ++k) {
                float w = W_in[(size_t)k * HDIM + t];
                a0 += sin_[0 * 131 + k] * w;
                a1 += sin_[1 * 131 + k] * w;
                a2 += sin_[2 * 131 + k] * w;
                a3 += sin_[3 * 131 + k] * w;
            }
            sA[0][t] = fmaxf(a0, 0.f); sA[1][t] = fmaxf(a1, 0.f);
            sA[2][t] = fmaxf(a2, 0.f); sA[3][t] = fmaxf(a3, 0.f);
        }
        __syncthreads();
        float a0 = 0.f, a1 = 0.f, a2 = 0.f, a3 = 0.f;
        for (int k4 = 0; k4 < HDIM / 4; ++k4) {
            float w0 = W_e1[(size_t)(k4 * 4 + 0) * HDIM + t];
            float w1 = W_e1[(size_t)(k4 * 4 + 1) * HDIM + t];
            float w2 = W_e1[(size_t)(k4 * 4 + 2) * HDIM + t];
            float w3 = W_e1[(size_t)(k4 * 4 + 3) * HDIM + t];
            float4 x0 = *reinterpret_cast<const float4*>(&sA[0][k4 * 4]);
            float4 x1 = *reinterpret_cast<const float4*>(&sA[1][k4 * 4]);
            float4 x2 = *reinterpret_cast<const float4*>(&sA[2][k4 * 4]);
            float4 x3 = *reinterpret_cast<const float4*>(&sA[3][k4 * 4]);
            a0 += x0.x * w0 + x0.y * w1 + x0.z * w2 + x0.w * w3;
            a1 += x1.x * w0 + x1.y * w1 + x1.z * w2 + x1.w * w3;
            a2 += x2.x * w0 + x2.y * w1 + x2.z * w2 + x2.w * w3;
            a3 += x3.x * w0 + x3.y * w1 + x3.z * w2 + x3.w * w3;
        }
        u[(size_t)(b0 + 0) * HDIM + t] = a0;
        u[(size_t)(b0 + 1) * HDIM + t] = a1;
        u[(size_t)(b0 + 2) * HDIM + t] = a2;
        u[(size_t)(b0 + 3) * HDIM + t] = a3;
    } else if (bx < 256) {
        // ---------------- role size head: 4 batches ------------------------
        int b0 = (bx - 192) * 4;
        float* sin_ = &sB[0][0];   // 524 floats
        float* s1b  = &sB[2][0];   // [4][256]
        float* slg  = &sB[0][0];   // reused after h (200 floats)
        for (int idx = t; idx < 4 * 131; idx += 512) {
            int bi = idx / 131, k = idx % 131;
            sin_[idx] = (k < LDIM) ? z[(size_t)(b0 + bi) * LDIM + k]
                                   : tp[(size_t)(b0 + bi) * PDIM + (k - LDIM)];
        }
        __syncthreads();
        {
            float bin = b_in[t];
            float a0 = bin, a1 = bin, a2 = bin, a3 = bin;
            for (int k = 0; k < LDIM + PDIM; ++k) {
                float w = W_in[(size_t)k * HDIM + t];
                a0 += sin_[0 * 131 + k] * w;
                a1 += sin_[1 * 131 + k] * w;
                a2 += sin_[2 * 131 + k] * w;
                a3 += sin_[3 * 131 + k] * w;
            }
            sA[0][t] = fmaxf(a0, 0.f); sA[1][t] = fmaxf(a1, 0.f);
            sA[2][t] = fmaxf(a2, 0.f); sA[3][t] = fmaxf(a3, 0.f);
        }
        __syncthreads();
        {
            int c = t & 255, bp = t >> 8;   // batches 2bp, 2bp+1
            float bv = b_s1[c];
            float a0 = bv, a1 = bv;
            for (int k = 0; k < HDIM; ++k) {
                float w = W_s1[(size_t)k * (HDIM / 2) + c];
                a0 += sA[2 * bp][k] * w;
                a1 += sA[2 * bp + 1][k] * w;
            }
            s1b[(2 * bp) * 256 + c] = fmaxf(a0, 0.f);
            s1b[(2 * bp + 1) * 256 + c] = fmaxf(a1, 0.f);
        }
        __syncthreads();
        int b4 = t / NDIM, o = t % NDIM;
        if (t < 4 * NDIM) {
            float a = b_s2[o];
            for (int k = 0; k < HDIM / 2; ++k)
                a += s1b[b4 * 256 + k] * W_s2[(size_t)k * NDIM + o];
            slg[b4 * NDIM + o] = a;
        }
        __syncthreads();
        if (t < 4 * NDIM) {
            float m = slg[b4 * NDIM];
            for (int k = 1; k < NDIM; ++k) m = fmaxf(m, slg[b4 * NDIM + k]);
            float s = 0.f;
            for (int k = 0; k < NDIM; ++k) s += expf(slg[b4 * NDIM + k] - m);
            out_sp[(size_t)(b0 + b4) * NDIM + o] = expf(slg[b4 * NDIM + o] - m) / s;
        }
    } else {
        // ---------------- role pW1: 0.5 * pe @ W1h, 4 rows -----------------
        int r0 = (bx - 256) * 4;
        int r[4];
#pragma unroll
        for (int q = 0; q < 4; ++q) { int rr = r0 + q; r[q] = (rr < NDIM) ? rr : NDIM - 1; }
        for (int idx = t; idx < 4 * HDIM; idx += 512)
            sA[idx >> 9][idx & 511] = pe[(size_t)r[idx >> 9] * HDIM + (idx & 511)];
        __syncthreads();
        float a0 = 0.f, a1 = 0.f, a2 = 0.f, a3 = 0.f;
        for (int k4 = 0; k4 < HDIM / 4; ++k4) {
            float w0 = W_e1[(size_t)(k4 * 4 + 0) * HDIM + t];
            float w1 = W_e1[(size_t)(k4 * 4 + 1) * HDIM + t];
            float w2 = W_e1[(size_t)(k4 * 4 + 2) * HDIM + t];
            float w3 = W_e1[(size_t)(k4 * 4 + 3) * HDIM + t];
            float4 x0 = *reinterpret_cast<const float4*>(&sA[0][k4 * 4]);
            float4 x1 = *reinterpret_cast<const float4*>(&sA[1][k4 * 4]);
            float4 x2 = *reinterpret_cast<const float4*>(&sA[2][k4 * 4]);
            float4 x3 = *reinterpret_cast<const float4*>(&sA[3][k4 * 4]);
            a0 += x0.x * w0 + x0.y * w1 + x0.z * w2 + x0.w * w3;
            a1 += x1.x * w0 + x1.y * w1 + x1.z * w2 + x1.w * w3;
            a2 += x2.x * w0 + x2.y * w1 + x2.z * w2 + x2.w * w3;
            a3 += x3.x * w0 + x3.y * w1 + x3.z * w2 + x3.w * w3;
        }
        pW1[(size_t)r[0] * HDIM + t] = 0.5f * a0;
        pW1[(size_t)r[1] * HDIM + t] = 0.5f * a1;
        pW1[(size_t)r[2] * HDIM + t] = 0.5f * a2;
        pW1[(size_t)r[3] * HDIM + t] = 0.5f * a3;
    }
}

// ============ k_edge: per (batch, r-half); all-produce then all-consume ====
// grid (256, 2), block 256. LDS 51.2KB -> 2 blocks/CU.
// Produce: thread (arr=t>>7, c=t&127) computes 50 rows of A or B chunk.
// Consume: 225 tasks of 2x3 edge tiles; 5 ds_read_b128 per r4 for 6 edges.
// Partial sums written to P[rhalf]; combined by k_comb.
__global__ __launch_bounds__(256) void k_edge(
        const float* __restrict__ nl,    // [256,50,32]
        const float* __restrict__ u,     // [256,512]
        const float* __restrict__ pW1,   // [50,512]
        const float* __restrict__ W_e1,  // [576,512]
        const float* __restrict__ b_e1,  // [512]
        const float* __restrict__ W_e2,  // [512,5]
        float* __restrict__ P) {         // [2][256][1225][5]
    int b  = blockIdx.x;
    int rh = blockIdx.y;
    int t  = threadIdx.x;
    int rbase = rh * 256;

    __shared__ float As[NDIM * CH];
    __shared__ float Bs[NDIM * CH];

    // task decode: (p, q): rows i0=2p,i0+1; cols j0=3q..3q+2; valid tiles only
    bool has = (t < 225);
    int pp = 0, qq = 0;
    if (has) {
        int tt = t;
        for (pp = 0; pp < 25; ++pp) {
            int qmin = pp ? ((2 * pp - 2) / 3 + 1) : 0;
            int cnt = 17 - qmin;
            if (tt < cnt) { qq = qmin + tt; break; }
            tt -= cnt;
        }
    }
    int i0 = 2 * pp, i1 = i0 + 1;
    int j0 = 3 * qq, j1 = j0 + 1, j2r = (3 * qq + 2 < NDIM) ? 3 * qq + 2 : NDIM - 1;

    float acc[6][EOUT];
#pragma unroll
    for (int e = 0; e < 6; ++e)
#pragma unroll
        for (int o = 0; o < EOUT; ++o) acc[e][o] = 0.f;

    int arr = t >> 7, c = t & 127;
    const float4* nl4 = reinterpret_cast<const float4*>(nl + (size_t)b * (NDIM * DDIM));

    for (int ch = 0; ch < 2; ++ch) {
        int col = rbase + ch * CH + c;
        // ---- produce ----
        {
            float w[DDIM];
#pragma unroll
            for (int k = 0; k < DDIM; ++k)
                w[k] = W_e1[(size_t)(HDIM + arr * DDIM + k) * HDIM + col];
            float cm = 0.5f * (u[(size_t)b * HDIM + col] + b_e1[col]);
            float* dst = arr ? Bs : As;
            for (int n = 0; n < NDIM; ++n) {
                float a = cm + pW1[(size_t)n * HDIM + col];
#pragma unroll
                for (int q8 = 0; q8 < 8; ++q8) {
                    float4 x = nl4[n * 8 + q8];   // wave-uniform -> s_load
                    a += x.x * w[4*q8] + x.y * w[4*q8+1] + x.z * w[4*q8+2] + x.w * w[4*q8+3];
                }
                dst[n * CH + ((((c >> 2) ^ (n & 7)) << 2) | (c & 3))] = a;
            }
        }
        __syncthreads();
        // ---- consume ----
        if (has) {
            const float4* A4 = reinterpret_cast<const float4*>(As);
            const float4* B4 = reinterpret_cast<const float4*>(Bs);
            const float* wch = W_e2 + (size_t)(rbase + ch * CH) * EOUT;
            for (int r4 = 0; r4 < CH / 4; ++r4) {
                const float* wr = wch + r4 * 4 * EOUT;   // uniform -> s_load
                float4 a0 = A4[i0 * 32 + (r4 ^ (i0 & 7))];
                float4 a1 = A4[i1 * 32 + (r4 ^ (i1 & 7))];
                float4 b0 = B4[j0 * 32 + (r4 ^ (j0 & 7))];
                float4 b1 = B4[j1 * 32 + (r4 ^ (j1 & 7))];
                float4 b2 = B4[j2r * 32 + (r4 ^ (j2r & 7))];
                float v[6][4];
#pragma unroll
                for (int rr = 0; rr < 4; ++rr) {
                    float av0 = (&a0.x)[rr], av1 = (&a1.x)[rr];
                    float bv0 = (&b0.x)[rr], bv1 = (&b1.x)[rr], bv2 = (&b2.x)[rr];
                    v[0][rr] = fmaxf(av0 + bv0, 0.f);
                    v[1][rr] = fmaxf(av0 + bv1, 0.f);
                    v[2][rr] = fmaxf(av0 + bv2, 0.f);
                    v[3][rr] = fmaxf(av1 + bv0, 0.f);
                    v[4][rr] = fmaxf(av1 + bv1, 0.f);
                    v[5][rr] = fmaxf(av1 + bv2, 0.f);
                }
#pragma unroll
                for (int rr = 0; rr < 4; ++rr) {
#pragma unroll
                    for (int o = 0; o < EOUT; ++o) {
                        float wv = wr[rr * EOUT + o];
#pragma unroll
                        for (int e = 0; e < 6; ++e)
                            acc[e][o] += v[e][rr] * wv;
                    }
                }
            }
        }
        __syncthreads();
    }

    if (has) {
        float* Pb = P + ((size_t)rh * BSZ + b) * NEDGE * EOUT;
        int js[3] = {j0, j1, 3 * qq + 2};
#pragma unroll
        for (int r = 0; r < 2; ++r) {
            int i = i0 + r;
#pragma unroll
            for (int cc = 0; cc < 3; ++cc) {
                int j = js[cc];
                if (i < j && j < NDIM) {
                    int e = i * (NDIM - 1) - (i * (i - 1)) / 2 + (j - i - 1);
#pragma unroll
                    for (int o = 0; o < EOUT; ++o)
                        Pb[(size_t)e * EOUT + o] = acc[r * 3 + cc][o];
                }
            }
        }
    }
}

// ============ k_comb: edge_logits = P0 + P1 + b_e2; + edge_indices =========
__global__ __launch_bounds__(256) void k_comb(const float* __restrict__ P,
                                              const float* __restrict__ b_e2,
                                              float* __restrict__ out_el,
                                              float* __restrict__ out_idx) {
    int blk = blockIdx.x, t = threadIdx.x;
    if (blk < 1225) {
        size_t eid = (size_t)blk * 256 + t;   // exactly 313600 = 1225*256
        const float* p0 = P + eid * EOUT;
        const float* p1 = P + (size_t)BSZ * NEDGE * EOUT + eid * EOUT;
        float* o = out_el + eid * EOUT;
#pragma unroll
        for (int q = 0; q < EOUT; ++q) o[q] = p0[q] + p1[q] + b_e2[q];
    } else {
        int e = (blk - 1225) * 256 + t;
        if (e < NEDGE) {
            int i = 0, rem = e;
            while (rem >= (NDIM - 1 - i)) { rem -= (NDIM - 1 - i); ++i; }
            int j = i + 1 + rem;
            out_idx[e * 2] = (float)i;
            out_idx[e * 2 + 1] = (float)j;
        }
    }
}

extern "C" void kernel_launch(void* const* d_in, const int* in_sizes, int n_in,
                              void* d_out, int out_size, void* d_ws, size_t ws_size,
                              hipStream_t stream) {
    const float* z    = (const float*)d_in[0];
    const float* tp   = (const float*)d_in[1];
    const float* W_in = (const float*)d_in[2];
    const float* b_in = (const float*)d_in[3];
    const float* W_s1 = (const float*)d_in[4];
    const float* b_s1 = (const float*)d_in[5];
    const float* W_s2 = (const float*)d_in[6];
    const float* b_s2 = (const float*)d_in[7];
    const float* W_n1 = (const float*)d_in[8];
    const float* b_n1 = (const float*)d_in[9];
    const float* W_n2 = (const float*)d_in[10];
    const float* b_n2 = (const float*)d_in[11];
    const float* W_e1 = (const float*)d_in[12];
    const float* b_e1 = (const float*)d_in[13];
    const float* W_e2 = (const float*)d_in[14];
    const float* b_e2 = (const float*)d_in[15];
    const float* pe   = (const float*)d_in[16];

    float* out     = (float*)d_out;
    float* out_nl  = out;                 // node_logits
    float* out_el  = out + 409600;        // edge_logits
    float* out_sp  = out + 1977600;       // size_probs
    float* out_idx = out + 1990400;       // edge_indices (as float)

    float* ws  = (float*)d_ws;
    float* u   = ws;
    float* pW1 = ws + 131072;
    float* P   = ws + 163840;             // [2][256][1225][5]

    k_front<<<269, 512, 0, stream>>>(z, tp, W_in, b_in, W_s1, b_s1, W_s2, b_s2,
                                     W_n1, b_n1, W_n2, b_n2, W_e1, pe,
                                     out_nl, out_sp, u, pW1);
    k_edge<<<dim3(BSZ, 2), 256, 0, stream>>>(out_nl, u, pW1, W_e1, b_e1, W_e2, P);
    k_comb<<<1230, 256, 0, stream>>>(P, b_e2, out_el, out_idx);
}

// Round 6
// 150.311 us; speedup vs baseline: 2.2346x; 1.0849x over previous
//
#include <hip/hip_runtime.h>
#include <math.h>

// Problem dims
#define BSZ   256
#define LDIM  128
#define PDIM  3
#define HDIM  512
#define DDIM  32
#define NDIM  50
#define NEDGE 1225   // N*(N-1)/2
#define EOUT  5      // EDIM+1
#define CH    128    // edge chunk cols

// out layout (floats)
//   node_logits  [256,50,32]   @ 0        (409600)
//   edge_logits  [256,1225,5]  @ 409600   (1568000)
//   size_probs   [256,50]      @ 1977600  (12800)
//   edge_indices [1225,2]      @ 1990400  (2450, float values)
// ws layout (floats): u @0 (131072), pW1 @131072 (25600), n1 @156672 (131072),
//                     P @287744 (2 x 1568000)

// ============ k_pre: balanced roles {h->n1, h->u, h->size, pW1} ============
// grid 205 x 512. Each role ~650 global loads/thread — no long tail.
__global__ __launch_bounds__(512) void k_pre(
        const float* __restrict__ z, const float* __restrict__ tp,
        const float* __restrict__ W_in, const float* __restrict__ b_in,
        const float* __restrict__ W_s1, const float* __restrict__ b_s1,
        const float* __restrict__ W_s2, const float* __restrict__ b_s2,
        const float* __restrict__ W_n1, const float* __restrict__ b_n1,
        const float* __restrict__ W_e1, const float* __restrict__ pe,
        float* __restrict__ n1, float* __restrict__ u,
        float* __restrict__ pW1, float* __restrict__ out_sp) {
    int bx = blockIdx.x, t = threadIdx.x;
    __shared__ float sA[4][HDIM];
    __shared__ float sB[4][HDIM];

    if (bx < 192) {
        // common: compute h for 4 batches into sA
        int role = bx >> 6;            // 0: n1, 1: u, 2: size
        int b0 = (bx & 63) * 4;
        float* sin_ = &sB[0][0];       // 524 floats
        for (int idx = t; idx < 4 * 131; idx += 512) {
            int bi = idx / 131, k = idx % 131;
            sin_[idx] = (k < LDIM) ? z[(size_t)(b0 + bi) * LDIM + k]
                                   : tp[(size_t)(b0 + bi) * PDIM + (k - LDIM)];
        }
        __syncthreads();
        {
            float bin = b_in[t];
            float a0 = bin, a1 = bin, a2 = bin, a3 = bin;
            for (int k = 0; k < LDIM + PDIM; ++k) {
                float w = W_in[(size_t)k * HDIM + t];
                a0 += sin_[0 * 131 + k] * w;
                a1 += sin_[1 * 131 + k] * w;
                a2 += sin_[2 * 131 + k] * w;
                a3 += sin_[3 * 131 + k] * w;
            }
            sA[0][t] = fmaxf(a0, 0.f); sA[1][t] = fmaxf(a1, 0.f);
            sA[2][t] = fmaxf(a2, 0.f); sA[3][t] = fmaxf(a3, 0.f);
        }
        __syncthreads();

        if (role == 0 || role == 1) {
            // n1 = relu(h@W_n1 + b_n1)  |  u = h@W1h  (W1h = rows 0..511 of W_e1)
            const float* W = (role == 0) ? W_n1 : W_e1;
            float a0 = 0.f, a1 = 0.f, a2 = 0.f, a3 = 0.f;
            for (int k4 = 0; k4 < HDIM / 4; ++k4) {
                float w0 = W[(size_t)(k4 * 4 + 0) * HDIM + t];
                float w1 = W[(size_t)(k4 * 4 + 1) * HDIM + t];
                float w2 = W[(size_t)(k4 * 4 + 2) * HDIM + t];
                float w3 = W[(size_t)(k4 * 4 + 3) * HDIM + t];
                float4 x0 = *reinterpret_cast<const float4*>(&sA[0][k4 * 4]);
                float4 x1 = *reinterpret_cast<const float4*>(&sA[1][k4 * 4]);
                float4 x2 = *reinterpret_cast<const float4*>(&sA[2][k4 * 4]);
                float4 x3 = *reinterpret_cast<const float4*>(&sA[3][k4 * 4]);
                a0 += x0.x * w0 + x0.y * w1 + x0.z * w2 + x0.w * w3;
                a1 += x1.x * w0 + x1.y * w1 + x1.z * w2 + x1.w * w3;
                a2 += x2.x * w0 + x2.y * w1 + x2.z * w2 + x2.w * w3;
                a3 += x3.x * w0 + x3.y * w1 + x3.z * w2 + x3.w * w3;
            }
            if (role == 0) {
                float bb = b_n1[t];
                n1[(size_t)(b0 + 0) * HDIM + t] = fmaxf(a0 + bb, 0.f);
                n1[(size_t)(b0 + 1) * HDIM + t] = fmaxf(a1 + bb, 0.f);
                n1[(size_t)(b0 + 2) * HDIM + t] = fmaxf(a2 + bb, 0.f);
                n1[(size_t)(b0 + 3) * HDIM + t] = fmaxf(a3 + bb, 0.f);
            } else {
                u[(size_t)(b0 + 0) * HDIM + t] = a0;
                u[(size_t)(b0 + 1) * HDIM + t] = a1;
                u[(size_t)(b0 + 2) * HDIM + t] = a2;
                u[(size_t)(b0 + 3) * HDIM + t] = a3;
            }
        } else {
            // size head: s1 = relu(h@W_s1+b), logits = s1@W_s2+b, softmax
            float* s1b = &sB[0][0];    // [4][256]
            float* slg = &sB[2][0];    // [4][50]
            {
                int c = t & 255, bp = t >> 8;   // batches 2bp, 2bp+1
                float bv = b_s1[c];
                float a0 = bv, a1 = bv;
                for (int k = 0; k < HDIM; ++k) {
                    float w = W_s1[(size_t)k * (HDIM / 2) + c];
                    a0 += sA[2 * bp][k] * w;
                    a1 += sA[2 * bp + 1][k] * w;
                }
                __syncthreads();
                s1b[(2 * bp) * 256 + c] = fmaxf(a0, 0.f);
                s1b[(2 * bp + 1) * 256 + c] = fmaxf(a1, 0.f);
            }
            __syncthreads();
            int b4 = t / NDIM, o = t % NDIM;
            if (t < 4 * NDIM) {
                float a = b_s2[o];
                for (int k = 0; k < HDIM / 2; ++k)
                    a += s1b[b4 * 256 + k] * W_s2[(size_t)k * NDIM + o];
                slg[b4 * NDIM + o] = a;
            }
            __syncthreads();
            if (t < 4 * NDIM) {
                float m = slg[b4 * NDIM];
                for (int k = 1; k < NDIM; ++k) m = fmaxf(m, slg[b4 * NDIM + k]);
                float s = 0.f;
                for (int k = 0; k < NDIM; ++k) s += expf(slg[b4 * NDIM + k] - m);
                out_sp[(size_t)(b0 + b4) * NDIM + o] = expf(slg[b4 * NDIM + o] - m) / s;
            }
        }
    } else {
        // ---------------- role pW1: 0.5 * pe @ W1h, 4 rows -----------------
        int r0 = (bx - 192) * 4;
        int r[4];
#pragma unroll
        for (int q = 0; q < 4; ++q) { int rr = r0 + q; r[q] = (rr < NDIM) ? rr : NDIM - 1; }
        for (int idx = t; idx < 4 * HDIM; idx += 512)
            sA[idx >> 9][idx & 511] = pe[(size_t)r[idx >> 9] * HDIM + (idx & 511)];
        __syncthreads();
        float a0 = 0.f, a1 = 0.f, a2 = 0.f, a3 = 0.f;
        for (int k4 = 0; k4 < HDIM / 4; ++k4) {
            float w0 = W_e1[(size_t)(k4 * 4 + 0) * HDIM + t];
            float w1 = W_e1[(size_t)(k4 * 4 + 1) * HDIM + t];
            float w2 = W_e1[(size_t)(k4 * 4 + 2) * HDIM + t];
            float w3 = W_e1[(size_t)(k4 * 4 + 3) * HDIM + t];
            float4 x0 = *reinterpret_cast<const float4*>(&sA[0][k4 * 4]);
            float4 x1 = *reinterpret_cast<const float4*>(&sA[1][k4 * 4]);
            float4 x2 = *reinterpret_cast<const float4*>(&sA[2][k4 * 4]);
            float4 x3 = *reinterpret_cast<const float4*>(&sA[3][k4 * 4]);
            a0 += x0.x * w0 + x0.y * w1 + x0.z * w2 + x0.w * w3;
            a1 += x1.x * w0 + x1.y * w1 + x1.z * w2 + x1.w * w3;
            a2 += x2.x * w0 + x2.y * w1 + x2.z * w2 + x2.w * w3;
            a3 += x3.x * w0 + x3.y * w1 + x3.z * w2 + x3.w * w3;
        }
        pW1[(size_t)r[0] * HDIM + t] = 0.5f * a0;
        pW1[(size_t)r[1] * HDIM + t] = 0.5f * a1;
        pW1[(size_t)r[2] * HDIM + t] = 0.5f * a2;
        pW1[(size_t)r[3] * HDIM + t] = 0.5f * a3;
    }
}

// ============ k_nl: [256,512]@[512,1600]+b, 4 batches/block ================
__global__ __launch_bounds__(320) void k_nl(const float* __restrict__ n1,
                                            const float* __restrict__ W_n2,
                                            const float* __restrict__ b_n2,
                                            float* __restrict__ out_nl) {
    const int NOUT = NDIM * DDIM;   // 1600
    int t = threadIdx.x;
    int j = blockIdx.x * 320 + t;
    int bg = blockIdx.y;            // 4 batches
    __shared__ float s[4 * HDIM];
    for (int idx = t; idx < 4 * HDIM / 4; idx += 320) {
        int lin = idx * 4;
        int row = lin >> 9, col = lin & 511;
        *reinterpret_cast<float4*>(&s[row * HDIM + col]) =
            *reinterpret_cast<const float4*>(&n1[(size_t)(bg * 4 + row) * HDIM + col]);
    }
    __syncthreads();
    float bias = b_n2[j];
    float acc[4] = {bias, bias, bias, bias};
    for (int k4 = 0; k4 < HDIM / 4; ++k4) {
        float w0 = W_n2[(size_t)(k4 * 4 + 0) * NOUT + j];
        float w1 = W_n2[(size_t)(k4 * 4 + 1) * NOUT + j];
        float w2 = W_n2[(size_t)(k4 * 4 + 2) * NOUT + j];
        float w3 = W_n2[(size_t)(k4 * 4 + 3) * NOUT + j];
#pragma unroll
        for (int b = 0; b < 4; ++b) {
            float4 nv = *reinterpret_cast<const float4*>(&s[b * HDIM + k4 * 4]);
            acc[b] += nv.x * w0 + nv.y * w1 + nv.z * w2 + nv.w * w3;
        }
    }
#pragma unroll
    for (int b = 0; b < 4; ++b)
        out_nl[(size_t)(bg * 4 + b) * NOUT + j] = acc[b];
}

// ============ k_edge: per (batch, r-half); all-produce then all-consume ====
__global__ __launch_bounds__(256) void k_edge(
        const float* __restrict__ nl,    // [256,50,32]
        const float* __restrict__ u,     // [256,512]
        const float* __restrict__ pW1,   // [50,512]
        const float* __restrict__ W_e1,  // [576,512]
        const float* __restrict__ b_e1,  // [512]
        const float* __restrict__ W_e2,  // [512,5]
        float* __restrict__ P) {         // [2][256][1225][5]
    int b  = blockIdx.x;
    int rh = blockIdx.y;
    int t  = threadIdx.x;
    int rbase = rh * 256;

    __shared__ float As[NDIM * CH];
    __shared__ float Bs[NDIM * CH];

    bool has = (t < 225);
    int pp = 0, qq = 0;
    if (has) {
        int tt = t;
        for (pp = 0; pp < 25; ++pp) {
            int qmin = pp ? ((2 * pp - 2) / 3 + 1) : 0;
            int cnt = 17 - qmin;
            if (tt < cnt) { qq = qmin + tt; break; }
            tt -= cnt;
        }
    }
    int i0 = 2 * pp, i1 = i0 + 1;
    int j0 = 3 * qq, j1 = j0 + 1, j2r = (3 * qq + 2 < NDIM) ? 3 * qq + 2 : NDIM - 1;

    float acc[6][EOUT];
#pragma unroll
    for (int e = 0; e < 6; ++e)
#pragma unroll
        for (int o = 0; o < EOUT; ++o) acc[e][o] = 0.f;

    int arr = t >> 7, c = t & 127;
    const float4* nl4 = reinterpret_cast<const float4*>(nl + (size_t)b * (NDIM * DDIM));

    for (int ch = 0; ch < 2; ++ch) {
        int col = rbase + ch * CH + c;
        {
            float w[DDIM];
#pragma unroll
            for (int k = 0; k < DDIM; ++k)
                w[k] = W_e1[(size_t)(HDIM + arr * DDIM + k) * HDIM + col];
            float cm = 0.5f * (u[(size_t)b * HDIM + col] + b_e1[col]);
            float* dst = arr ? Bs : As;
            for (int n = 0; n < NDIM; ++n) {
                float a = cm + pW1[(size_t)n * HDIM + col];
#pragma unroll
                for (int q8 = 0; q8 < 8; ++q8) {
                    float4 x = nl4[n * 8 + q8];   // wave-uniform -> s_load
                    a += x.x * w[4*q8] + x.y * w[4*q8+1] + x.z * w[4*q8+2] + x.w * w[4*q8+3];
                }
                dst[n * CH + ((((c >> 2) ^ (n & 7)) << 2) | (c & 3))] = a;
            }
        }
        __syncthreads();
        if (has) {
            const float4* A4 = reinterpret_cast<const float4*>(As);
            const float4* B4 = reinterpret_cast<const float4*>(Bs);
            const float* wch = W_e2 + (size_t)(rbase + ch * CH) * EOUT;
            for (int r4 = 0; r4 < CH / 4; ++r4) {
                const float* wr = wch + r4 * 4 * EOUT;   // uniform -> s_load
                float4 a0 = A4[i0 * 32 + (r4 ^ (i0 & 7))];
                float4 a1 = A4[i1 * 32 + (r4 ^ (i1 & 7))];
                float4 b0 = B4[j0 * 32 + (r4 ^ (j0 & 7))];
                float4 b1 = B4[j1 * 32 + (r4 ^ (j1 & 7))];
                float4 b2 = B4[j2r * 32 + (r4 ^ (j2r & 7))];
                float v[6][4];
#pragma unroll
                for (int rr = 0; rr < 4; ++rr) {
                    float av0 = (&a0.x)[rr], av1 = (&a1.x)[rr];
                    float bv0 = (&b0.x)[rr], bv1 = (&b1.x)[rr], bv2 = (&b2.x)[rr];
                    v[0][rr] = fmaxf(av0 + bv0, 0.f);
                    v[1][rr] = fmaxf(av0 + bv1, 0.f);
                    v[2][rr] = fmaxf(av0 + bv2, 0.f);
                    v[3][rr] = fmaxf(av1 + bv0, 0.f);
                    v[4][rr] = fmaxf(av1 + bv1, 0.f);
                    v[5][rr] = fmaxf(av1 + bv2, 0.f);
                }
#pragma unroll
                for (int rr = 0; rr < 4; ++rr) {
#pragma unroll
                    for (int o = 0; o < EOUT; ++o) {
                        float wv = wr[rr * EOUT + o];
#pragma unroll
                        for (int e = 0; e < 6; ++e)
                            acc[e][o] += v[e][rr] * wv;
                    }
                }
            }
        }
        __syncthreads();
    }

    if (has) {
        float* Pb = P + ((size_t)rh * BSZ + b) * NEDGE * EOUT;
        int js[3] = {j0, j1, 3 * qq + 2};
#pragma unroll
        for (int r = 0; r < 2; ++r) {
            int i = i0 + r;
#pragma unroll
            for (int cc = 0; cc < 3; ++cc) {
                int j = js[cc];
                if (i < j && j < NDIM) {
                    int e = i * (NDIM - 1) - (i * (i - 1)) / 2 + (j - i - 1);
#pragma unroll
                    for (int o = 0; o < EOUT; ++o)
                        Pb[(size_t)e * EOUT + o] = acc[r * 3 + cc][o];
                }
            }
        }
    }
}

// ============ k_comb: out_el = P0 + P1 + bias (float4 x5 per thread) =======
__global__ __launch_bounds__(256) void k_comb(const float* __restrict__ P,
                                              const float* __restrict__ b_e2,
                                              float* __restrict__ out_el,
                                              float* __restrict__ out_idx) {
    int blk = blockIdx.x, t = threadIdx.x;
    if (blk < 307) {
        int tid = blk * 256 + t;       // 20 floats per thread; 78400 total
        if (tid < 78400) {
            const float4* p0 = reinterpret_cast<const float4*>(P) + (size_t)tid * 5;
            const float4* p1 = reinterpret_cast<const float4*>(P + (size_t)BSZ * NEDGE * EOUT)
                               + (size_t)tid * 5;
            float4* o = reinterpret_cast<float4*>(out_el) + (size_t)tid * 5;
            float b5[5];
#pragma unroll
            for (int c = 0; c < 5; ++c) b5[c] = b_e2[c];
#pragma unroll
            for (int q = 0; q < 5; ++q) {
                float4 a = p0[q], b = p1[q];
                float4 r;
                r.x = a.x + b.x + b5[(q * 4 + 0) % 5];
                r.y = a.y + b.y + b5[(q * 4 + 1) % 5];
                r.z = a.z + b.z + b5[(q * 4 + 2) % 5];
                r.w = a.w + b.w + b5[(q * 4 + 3) % 5];
                o[q] = r;
            }
        }
    } else {
        int e = (blk - 307) * 256 + t;
        if (e < NEDGE) {
            int i = 0, rem = e;
            while (rem >= (NDIM - 1 - i)) { rem -= (NDIM - 1 - i); ++i; }
            int j = i + 1 + rem;
            out_idx[e * 2] = (float)i;
            out_idx[e * 2 + 1] = (float)j;
        }
    }
}

extern "C" void kernel_launch(void* const* d_in, const int* in_sizes, int n_in,
                              void* d_out, int out_size, void* d_ws, size_t ws_size,
                              hipStream_t stream) {
    const float* z    = (const float*)d_in[0];
    const float* tp   = (const float*)d_in[1];
    const float* W_in = (const float*)d_in[2];
    const float* b_in = (const float*)d_in[3];
    const float* W_s1 = (const float*)d_in[4];
    const float* b_s1 = (const float*)d_in[5];
    const float* W_s2 = (const float*)d_in[6];
    const float* b_s2 = (const float*)d_in[7];
    const float* W_n1 = (const float*)d_in[8];
    const float* b_n1 = (const float*)d_in[9];
    const float* W_n2 = (const float*)d_in[10];
    const float* b_n2 = (const float*)d_in[11];
    const float* W_e1 = (const float*)d_in[12];
    const float* b_e1 = (const float*)d_in[13];
    const float* W_e2 = (const float*)d_in[14];
    const float* b_e2 = (const float*)d_in[15];
    const float* pe   = (const float*)d_in[16];

    float* out     = (float*)d_out;
    float* out_nl  = out;                 // node_logits
    float* out_el  = out + 409600;        // edge_logits
    float* out_sp  = out + 1977600;       // size_probs
    float* out_idx = out + 1990400;       // edge_indices (as float)

    float* ws  = (float*)d_ws;
    float* u   = ws;
    float* pW1 = ws + 131072;
    float* n1  = ws + 156672;
    float* P   = ws + 287744;             // [2][256][1225][5]

    k_pre<<<205, 512, 0, stream>>>(z, tp, W_in, b_in, W_s1, b_s1, W_s2, b_s2,
                                   W_n1, b_n1, W_e1, pe, n1, u, pW1, out_sp);
    k_nl<<<dim3(5, 64), 320, 0, stream>>>(n1, W_n2, b_n2, out_nl);
    k_edge<<<dim3(BSZ, 2), 256, 0, stream>>>(out_nl, u, pW1, W_e1, b_e1, W_e2, P);
    k_comb<<<312, 256, 0, stream>>>(P, b_e2, out_el, out_idx);
}